// Round 3
// baseline (39178.067 us; speedup 1.0000x reference)
//
#include <hip/hip_runtime.h>
#include <hip/hip_bf16.h>

typedef __hip_bfloat16 bf16;

__device__ __forceinline__ float toF(float v) { return v; }
__device__ __forceinline__ float toF(bf16 v) { return __bfloat162float(v); }

// All conv kernels operate on a SINGLE image (batch handled by host loop)
// to keep peak workspace ~20-40 MB. All inputs/outputs are FLOAT32.

// ---------------------------------------------------------------------------
// conv1: 4x4 stride2 pad1, Cin=3 Cout=128, 512x512 -> 256x256, bias+ReLU
// ---------------------------------------------------------------------------
template <typename OutT>
__global__ void conv1_k(const float* __restrict__ x, const float* __restrict__ w,
                        const float* __restrict__ bias, OutT* __restrict__ out)
{
    int idx = blockIdx.x * 256 + threadIdx.x;      // 128*256*256 = 2^23
    int ow = idx & 255;
    int oh = (idx >> 8) & 255;
    int co = idx >> 16;                            // 0..127
    float acc = bias[co];
    const float* wp = w + co * 48;
    for (int ci = 0; ci < 3; ++ci) {
        const float* xp = x + (size_t)ci * 512 * 512;
        const float* wc = wp + ci * 16;
        #pragma unroll
        for (int kh = 0; kh < 4; ++kh) {
            int ih = oh * 2 - 1 + kh;
            if ((unsigned)ih < 512u) {
                const float* row = xp + ih * 512;
                const float* wr = wc + kh * 4;
                #pragma unroll
                for (int kw = 0; kw < 4; ++kw) {
                    int iw = ow * 2 - 1 + kw;
                    if ((unsigned)iw < 512u)
                        acc += row[iw] * wr[kw];
                }
            }
        }
    }
    out[idx] = (OutT)fmaxf(acc, 0.f);
}

// ---------------------------------------------------------------------------
// conv2: 7x7 stride4 pad2, Cin=128 Cout=256, 256x256 -> 64x64, bias+ReLU
// ---------------------------------------------------------------------------
template <typename InT, typename OutT>
__global__ void conv2_k(const InT* __restrict__ in, const float* __restrict__ w,
                        const float* __restrict__ bias, OutT* __restrict__ out)
{
    int idx = blockIdx.x * 256 + threadIdx.x;      // 256*64*64 = 2^20
    int ow = idx & 63;
    int oh = (idx >> 6) & 63;
    int co = idx >> 12;                            // 0..255
    float acc = bias[co];
    int ih0 = oh * 4 - 2, iw0 = ow * 4 - 2;
    bool interior = (ih0 >= 0) && (ih0 + 6 < 256) && (iw0 >= 0) && (iw0 + 6 < 256);
    const float* wbase = w + (size_t)co * 128 * 49;
    if (interior) {
        for (int ci = 0; ci < 128; ++ci) {
            const InT* ip = in + (size_t)ci * 65536 + ih0 * 256 + iw0;
            const float* wp = wbase + ci * 49;
            #pragma unroll
            for (int kh = 0; kh < 7; ++kh) {
                const InT* row = ip + kh * 256;
                const float* wr = wp + kh * 7;
                #pragma unroll
                for (int kw = 0; kw < 7; ++kw)
                    acc += toF(row[kw]) * wr[kw];
            }
        }
    } else {
        for (int ci = 0; ci < 128; ++ci) {
            const InT* ip = in + (size_t)ci * 65536;
            const float* wp = wbase + ci * 49;
            for (int kh = 0; kh < 7; ++kh) {
                int ih = ih0 + kh;
                if ((unsigned)ih < 256u) {
                    const InT* row = ip + ih * 256;
                    const float* wr = wp + kh * 7;
                    for (int kw = 0; kw < 7; ++kw) {
                        int iw = iw0 + kw;
                        if ((unsigned)iw < 256u)
                            acc += toF(row[iw]) * wr[kw];
                    }
                }
            }
        }
    }
    out[idx] = (OutT)fmaxf(acc, 0.f);
}

// ---------------------------------------------------------------------------
// conv3: 7x7 stride4 pad2, Cin=256 Cout=256, 64x64 -> 16x16, bias+ReLU
// ---------------------------------------------------------------------------
template <typename InT>
__global__ void conv3_k(const InT* __restrict__ in, const float* __restrict__ w,
                        const float* __restrict__ bias, float* __restrict__ out)
{
    int idx = blockIdx.x * 256 + threadIdx.x;      // 256*16*16 = 65536
    int ow = idx & 15;
    int oh = (idx >> 4) & 15;
    int co = idx >> 8;                             // 0..255
    float acc = bias[co];
    int ih0 = oh * 4 - 2, iw0 = ow * 4 - 2;
    const float* wbase = w + (size_t)co * 256 * 49;
    for (int ci = 0; ci < 256; ++ci) {
        const InT* ip = in + (size_t)ci * 4096;
        const float* wp = wbase + ci * 49;
        for (int kh = 0; kh < 7; ++kh) {
            int ih = ih0 + kh;
            if ((unsigned)ih < 64u) {
                const InT* row = ip + ih * 64;
                const float* wr = wp + kh * 7;
                for (int kw = 0; kw < 7; ++kw) {
                    int iw = iw0 + kw;
                    if ((unsigned)iw < 64u)
                        acc += toF(row[iw]) * wr[kw];
                }
            }
        }
    }
    out[idx] = fmaxf(acc, 0.f);
}

// ---------------------------------------------------------------------------
// conv4: 3x3 stride2 pad1, Cin=256 Cout=256, 16x16 -> 8x8, bias+ReLU
// ---------------------------------------------------------------------------
__global__ void conv4_k(const float* __restrict__ in, const float* __restrict__ w,
                        const float* __restrict__ bias, float* __restrict__ out)
{
    int idx = blockIdx.x * 256 + threadIdx.x;      // 256*8*8 = 16384
    int ow = idx & 7;
    int oh = (idx >> 3) & 7;
    int co = idx >> 6;                             // 0..255
    float acc = bias[co];
    const float* wbase = w + (size_t)co * 256 * 9;
    for (int ci = 0; ci < 256; ++ci) {
        const float* ip = in + (size_t)ci * 256;
        const float* wp = wbase + ci * 9;
        #pragma unroll
        for (int kh = 0; kh < 3; ++kh) {
            int ih = oh * 2 - 1 + kh;
            if ((unsigned)ih < 16u) {
                #pragma unroll
                for (int kw = 0; kw < 3; ++kw) {
                    int iw = ow * 2 - 1 + kw;
                    if ((unsigned)iw < 16u)
                        acc += ip[ih * 16 + iw] * wp[kh * 3 + kw];
                }
            }
        }
    }
    out[idx] = fmaxf(acc, 0.f);
}

// ---------------------------------------------------------------------------
// residual part a: t1 = conv1x3 (pad W=1) over relu(h), 256 -> 1024, 8x8
// ---------------------------------------------------------------------------
__global__ void resa_k(const float* __restrict__ h, const float* __restrict__ w,
                       float* __restrict__ t1)
{
    int idx = blockIdx.x * 256 + threadIdx.x;      // 1024*8*8 = 65536
    int x = idx & 7;
    int y = (idx >> 3) & 7;
    int co = idx >> 6;                             // 0..1023
    float acc = 0.f;
    const float* wbase = w + (size_t)co * 256 * 3;
    for (int ci = 0; ci < 256; ++ci) {
        const float* row = h + (size_t)ci * 64 + y * 8;
        const float* wp = wbase + ci * 3;
        #pragma unroll
        for (int kx = 0; kx < 3; ++kx) {
            int xx = x - 1 + kx;
            if ((unsigned)xx < 8u)
                acc += fmaxf(row[xx], 0.f) * wp[kx];
        }
    }
    t1[idx] = acc;
}

// ---------------------------------------------------------------------------
// residual part b: h_new = h_old + conv1x1 over relu(t1), 1024 -> 256, 8x8
// ---------------------------------------------------------------------------
__global__ void resb_k(const float* __restrict__ h_old, const float* __restrict__ t1,
                       const float* __restrict__ w, float* __restrict__ h_new)
{
    int idx = blockIdx.x * 256 + threadIdx.x;      // 256*8*8 = 16384
    int x = idx & 7;
    int y = (idx >> 3) & 7;
    int co = idx >> 6;                             // 0..255
    float acc = h_old[idx];
    const float* tbase = t1 + y * 8 + x;
    const float* wp = w + (size_t)co * 1024;
    for (int ci = 0; ci < 1024; ++ci)
        acc += fmaxf(tbase[(size_t)ci * 64], 0.f) * wp[ci];
    h_new[idx] = acc;
}

// ---------------------------------------------------------------------------
// emb norms: en[k] = sum_d emb[k,d]^2   (K=512, D=256)
// ---------------------------------------------------------------------------
__global__ void embnorm_k(const float* __restrict__ emb, float* __restrict__ en)
{
    int k = blockIdx.x * 256 + threadIdx.x;        // 512
    const float* e = emb + (size_t)k * 256;
    float s = 0.f;
    for (int d = 0; d < 256; ++d) { float v = e[d]; s += v * v; }
    en[k] = s;
}

// ---------------------------------------------------------------------------
// VQ over full batch h6 [8,256,8,8]: one block per latent row (512 rows).
// dist_k = ||e_k||^2 - 2 lat.e_k (|lat|^2 is row-constant, argmin-invariant).
// Tie-break lowest index (matches jnp.argmin).
// ---------------------------------------------------------------------------
__global__ void vq_k(const float* __restrict__ h, const float* __restrict__ emb,
                     const float* __restrict__ en, float* __restrict__ out,
                     float* __restrict__ mse_acc, int* __restrict__ hist)
{
    int row = blockIdx.x;                          // 512 = 8*8*8
    int b = row >> 6, y = (row >> 3) & 7, xx = row & 7;
    int t = threadIdx.x;                           // 256
    __shared__ float lat[256];
    __shared__ float sdist[256];
    __shared__ int   sidx[256];

    float l = fmaxf(h[((size_t)(b * 256 + t) * 8 + y) * 8 + xx], 0.f);
    lat[t] = l;
    __syncthreads();

    float d0 = 0.f, d1 = 0.f;
    const float* e0 = emb + (size_t)t * 256;
    const float* e1 = emb + (size_t)(t + 256) * 256;
    for (int d = 0; d < 256; ++d) {
        float lv = lat[d];
        d0 += lv * e0[d];
        d1 += lv * e1[d];
    }
    d0 = en[t] - 2.f * d0;
    d1 = en[t + 256] - 2.f * d1;
    float best_d = d0; int best_i = t;
    if (d1 < best_d) { best_d = d1; best_i = t + 256; }
    sdist[t] = best_d; sidx[t] = best_i;
    __syncthreads();
    for (int s = 128; s > 0; s >>= 1) {
        if (t < s) {
            float od = sdist[t + s]; int oi = sidx[t + s];
            if (od < sdist[t] || (od == sdist[t] && oi < sidx[t])) {
                sdist[t] = od; sidx[t] = oi;
            }
        }
        __syncthreads();
    }
    int idx = sidx[0];

    float q = emb[(size_t)idx * 256 + t];
    out[((size_t)(b * 256 + t) * 8 + y) * 8 + xx] = q;
    float diff = q - lat[t];
    __syncthreads();
    sdist[t] = diff * diff;
    __syncthreads();
    for (int s = 128; s > 0; s >>= 1) {
        if (t < s) sdist[t] += sdist[t + s];
        __syncthreads();
    }
    if (t == 0) {
        atomicAdd(mse_acc, sdist[0]);
        atomicAdd(&hist[idx], 1);
    }
}

// ---------------------------------------------------------------------------
// epilogue: loss = 2*mse/(512*256); perplexity = exp(-sum p log(p+1e-10))
// ---------------------------------------------------------------------------
__global__ void final_k(const float* __restrict__ mse_acc, const int* __restrict__ hist,
                        float* __restrict__ out)
{
    __shared__ float sh[512];
    int t = threadIdx.x;                           // 512
    float p = (float)hist[t] / 512.f;
    sh[t] = p * logf(p + 1e-10f);
    __syncthreads();
    for (int s = 256; s > 0; s >>= 1) {
        if (t < s) sh[t] += sh[t + s];
        __syncthreads();
    }
    if (t == 0) {
        float loss = 2.f * mse_acc[0] / (512.f * 256.f);
        float perp = expf(-sh[0]);
        out[131072] = loss;
        out[131073] = perp;
    }
}

// ---------------------------------------------------------------------------
extern "C" void kernel_launch(void* const* d_in, const int* in_sizes, int n_in,
                              void* d_out, int out_size, void* d_ws, size_t ws_size,
                              hipStream_t stream)
{
    const float* x    = (const float*)d_in[0];
    const float* w_in = (const float*)d_in[1];
    const float* b_in = (const float*)d_in[2];
    const float* w_h1 = (const float*)d_in[3];
    const float* b_h1 = (const float*)d_in[4];
    const float* w_h2 = (const float*)d_in[5];
    const float* b_h2 = (const float*)d_in[6];
    const float* w_h3 = (const float*)d_in[7];
    const float* b_h3 = (const float*)d_in[8];
    const float* r0w1 = (const float*)d_in[9];
    const float* r0w2 = (const float*)d_in[10];
    const float* r1w1 = (const float*)d_in[11];
    const float* r1w2 = (const float*)d_in[12];
    const float* emb  = (const float*)d_in[13];
    float* out = (float*)d_out;

    char* ws = (char*)d_ws;
    size_t off = 0;
    auto alloc = [&](size_t bytes) -> void* {
        void* p = ws + off;
        off += (bytes + 255) & ~(size_t)255;
        return p;
    };

    // Per-image staging sizes (elements)
    const size_t H1N = 128ull * 256 * 256;   // 8.39M
    const size_t H2N = 256ull * 64 * 64;     // 1.05M
    const size_t H3N = 65536, H4N = 16384, T1N = 65536;

    // Persistent small buffers first
    float* h6  = (float*)alloc(131072ull * 4);   // [8,256,8,8] full batch
    float* en  = (float*)alloc(512 * 4);
    float* mse = (float*)alloc(256);
    int*  hist = (int*)alloc(512 * 4);
    float* h3  = (float*)alloc(H3N * 4);
    float* h4  = (float*)alloc(H4N * 4);
    float* t1  = (float*)alloc(T1N * 4);
    float* h5  = (float*)alloc(H4N * 4);
    size_t small_end = off;

    // Tier selection by ws_size: A = f32 h1+h2 (~39MB), B = bf16 h1 + f32 h2
    // (~22MB), C = bf16 h1+h2 (~20MB). Deterministic per call.
    size_t needA = small_end + H1N * 4 + H2N * 4 + 4096;
    size_t needB = small_end + H1N * 2 + H2N * 4 + 4096;
    int tier = (ws_size >= needA) ? 0 : (ws_size >= needB) ? 1 : 2;

    void* h1 = alloc(tier == 0 ? H1N * 4 : H1N * 2);
    void* h2 = alloc(tier <= 1 ? H2N * 4 : H2N * 2);

    hipMemsetAsync(mse, 0, 4, stream);
    hipMemsetAsync(hist, 0, 512 * 4, stream);

    for (int n = 0; n < 8; ++n) {
        const float* xn = x + (size_t)n * 3 * 512 * 512;
        float* h6n = h6 + (size_t)n * 16384;

        if (tier == 0) {
            conv1_k<float><<<32768, 256, 0, stream>>>(xn, w_in, b_in, (float*)h1);
            conv2_k<float, float><<<4096, 256, 0, stream>>>((const float*)h1, w_h1, b_h1, (float*)h2);
            conv3_k<float><<<256, 256, 0, stream>>>((const float*)h2, w_h2, b_h2, h3);
        } else if (tier == 1) {
            conv1_k<bf16><<<32768, 256, 0, stream>>>(xn, w_in, b_in, (bf16*)h1);
            conv2_k<bf16, float><<<4096, 256, 0, stream>>>((const bf16*)h1, w_h1, b_h1, (float*)h2);
            conv3_k<float><<<256, 256, 0, stream>>>((const float*)h2, w_h2, b_h2, h3);
        } else {
            conv1_k<bf16><<<32768, 256, 0, stream>>>(xn, w_in, b_in, (bf16*)h1);
            conv2_k<bf16, bf16><<<4096, 256, 0, stream>>>((const bf16*)h1, w_h1, b_h1, (bf16*)h2);
            conv3_k<bf16><<<256, 256, 0, stream>>>((const bf16*)h2, w_h2, b_h2, h3);
        }
        conv4_k<<<64, 256, 0, stream>>>(h3, w_h3, b_h3, h4);

        resa_k<<<256, 256, 0, stream>>>(h4, r0w1, t1);
        resb_k<<<64, 256, 0, stream>>>(h4, t1, r0w2, h5);
        resa_k<<<256, 256, 0, stream>>>(h5, r1w1, t1);
        resb_k<<<64, 256, 0, stream>>>(h5, t1, r1w2, h6n);
    }

    embnorm_k<<<2, 256, 0, stream>>>(emb, en);
    vq_k<<<512, 256, 0, stream>>>(h6, emb, en, out, mse, hist);
    final_k<<<1, 512, 0, stream>>>(mse, hist, out);
}

// Round 4
// 6529.648 us; speedup vs baseline: 6.0000x; 6.0000x over previous
//
#include <hip/hip_runtime.h>
#include <hip/hip_bf16.h>

typedef __hip_bfloat16 bf16;

__device__ __forceinline__ float toF(float v) { return v; }
__device__ __forceinline__ float toF(bf16 v) { return __bfloat162float(v); }

// ===========================================================================
// conv1: 4x4 s2 p1, Cin=3 Cout=128, 512->256. Per image. LDS input tile,
// 2x2 outputs/thread, block tile = 32x32 outputs for one co.
// grid: 8 tx * 8 ty * 128 co = 8192 blocks
// ===========================================================================
template <typename OutT>
__global__ __launch_bounds__(256) void conv1t_k(const float* __restrict__ x,
        const float* __restrict__ w, const float* __restrict__ bias,
        OutT* __restrict__ out)
{
    int bid = blockIdx.x;
    int tx = bid & 7, ty = (bid >> 3) & 7, co = bid >> 6;   // co 0..127
    int oh0 = ty * 32, ow0 = tx * 32;
    int t = threadIdx.x;
    int oyp = t >> 4, oxp = t & 15;          // 16x16 thread grid, 2x2 out each

    __shared__ __align__(16) float st[66 * 68];

    float b = bias[co];
    float acc[2][2] = {{b, b}, {b, b}};
    int ihb = oh0 * 2 - 1, iwb = ow0 * 2 - 1;

    for (int ci = 0; ci < 3; ++ci) {
        __syncthreads();
        for (int i = t; i < 66 * 68; i += 256) {
            int r = i / 68, c = i - r * 68;
            float v = 0.f;
            if (c < 66) {
                int ih = ihb + r, iw = iwb + c;
                if ((unsigned)ih < 512u && (unsigned)iw < 512u)
                    v = x[ci * 262144 + ih * 512 + iw];
            }
            st[i] = v;
        }
        __syncthreads();
        float wr[16];
        #pragma unroll
        for (int k = 0; k < 16; ++k) wr[k] = w[co * 48 + ci * 16 + k];
        #pragma unroll
        for (int rr = 0; rr < 6; ++rr) {
            int r = oyp * 4 + rr;
            int c0 = oxp * 4;
            float2 v01 = *(const float2*)&st[r * 68 + c0];
            float2 v23 = *(const float2*)&st[r * 68 + c0 + 2];
            float2 v45 = *(const float2*)&st[r * 68 + c0 + 4];
            float v[6] = {v01.x, v01.y, v23.x, v23.y, v45.x, v45.y};
            #pragma unroll
            for (int oy = 0; oy < 2; ++oy) {
                int kh = rr - oy * 2;
                if (kh >= 0 && kh < 4) {
                    #pragma unroll
                    for (int ox = 0; ox < 2; ++ox)
                        #pragma unroll
                        for (int kw = 0; kw < 4; ++kw)
                            acc[oy][ox] += v[ox * 2 + kw] * wr[kh * 4 + kw];
                }
            }
        }
    }
    #pragma unroll
    for (int oy = 0; oy < 2; ++oy)
        #pragma unroll
        for (int ox = 0; ox < 2; ++ox) {
            int oh = oh0 + oyp * 2 + oy, ow = ow0 + oxp * 2 + ox;
            out[co * 65536 + oh * 256 + ow] = (OutT)fmaxf(acc[oy][ox], 0.f);
        }
}

// ===========================================================================
// conv2 tiled: 7x7 s4 p2, Cin=128 Cout=256, 256->64. Per image, K-split 2,
// f32 atomic partials. Block: 64co x (8x8)px, thread: 8co x 2px.
// grid: 4 cot * 64 pxt * 2 split = 512 blocks
// ===========================================================================
template <typename InT>
__global__ __launch_bounds__(256) void conv2t_k(const InT* __restrict__ in,
        const float* __restrict__ w, float* __restrict__ p2)
{
    int bid = blockIdx.x;
    int cot = bid & 3;
    int pxt = (bid >> 2) & 63;
    int split = bid >> 8;                  // 0..1
    int co0 = cot * 64;
    int oh0 = (pxt >> 3) * 8, ow0 = (pxt & 7) * 8;
    int ci0 = split * 64;
    int t = threadIdx.x;
    int copg = t >> 5;                     // 0..7
    int pxg = t & 31;
    int py = pxg >> 2;                     // 0..7
    int pxl0 = (pxg & 3) * 2;              // 0,2,4,6

    __shared__ __align__(16) float pt[35 * 37];
    __shared__ __align__(16) float wl[48 * 68 + 64];

    float acc[8][2];
    #pragma unroll
    for (int o = 0; o < 8; ++o) { acc[o][0] = 0.f; acc[o][1] = 0.f; }

    int ihb = oh0 * 4 - 2, iwb = ow0 * 4 - 2;

    for (int ci = 0; ci < 64; ++ci) {
        int cig = ci0 + ci;
        __syncthreads();
        for (int i = t; i < 1225; i += 256) {
            int r = i / 35, c = i - r * 35;
            int ih = ihb + r, iw = iwb + c;
            float v = 0.f;
            if ((unsigned)ih < 256u && (unsigned)iw < 256u)
                v = toF(in[cig * 65536 + ih * 256 + iw]);
            pt[r * 37 + c] = v;
        }
        for (int i = t; i < 3136; i += 256) {
            int co = i / 49, tap = i - co * 49;
            wl[tap * 68 + co] = w[(size_t)(co0 + co) * 6272 + cig * 49 + tap];
        }
        __syncthreads();
        #pragma unroll
        for (int kh = 0; kh < 7; ++kh) {
            #pragma unroll
            for (int kw = 0; kw < 7; ++kw) {
                int tap = kh * 7 + kw;
                float4 w0 = *(const float4*)&wl[tap * 68 + copg * 8];
                float4 w1 = *(const float4*)&wl[tap * 68 + copg * 8 + 4];
                float p0 = pt[(py * 4 + kh) * 37 + pxl0 * 4 + kw];
                float p1 = pt[(py * 4 + kh) * 37 + (pxl0 + 1) * 4 + kw];
                acc[0][0] += w0.x * p0; acc[0][1] += w0.x * p1;
                acc[1][0] += w0.y * p0; acc[1][1] += w0.y * p1;
                acc[2][0] += w0.z * p0; acc[2][1] += w0.z * p1;
                acc[3][0] += w0.w * p0; acc[3][1] += w0.w * p1;
                acc[4][0] += w1.x * p0; acc[4][1] += w1.x * p1;
                acc[5][0] += w1.y * p0; acc[5][1] += w1.y * p1;
                acc[6][0] += w1.z * p0; acc[6][1] += w1.z * p1;
                acc[7][0] += w1.w * p0; acc[7][1] += w1.w * p1;
            }
        }
    }
    #pragma unroll
    for (int o = 0; o < 8; ++o)
        #pragma unroll
        for (int j = 0; j < 2; ++j) {
            int co = co0 + copg * 8 + o;
            int oh = oh0 + py, ow = ow0 + pxl0 + j;
            atomicAdd(&p2[co * 4096 + oh * 64 + ow], acc[o][j]);
        }
}

// combine2: h2[img] = relu(bias + p2), 1048576 elems
template <typename OutT>
__global__ void combine2_k(const float* __restrict__ p2, const float* __restrict__ bias,
                           OutT* __restrict__ h2img)
{
    int idx = blockIdx.x * 256 + threadIdx.x;
    int co = idx >> 12;
    h2img[idx] = (OutT)fmaxf(bias[co] + p2[idx], 0.f);
}

// ===========================================================================
// conv3 tiled: 7x7 s4 p2, Cin=256 Cout=256, 64->16. Batched imgs, K-split 16.
// Block: 64co x 256px (whole image), thread: 8co x 8px.
// grid: 4 cot * 8 img * 16 split = 512 blocks
// ===========================================================================
template <typename InT>
__global__ __launch_bounds__(256) void conv3t_k(const InT* __restrict__ in,
        const float* __restrict__ w, float* __restrict__ p3)
{
    int bid = blockIdx.x;
    int cot = bid & 3;
    int img = (bid >> 2) & 7;
    int split = bid >> 5;                  // 0..15
    int co0 = cot * 64;
    int ci0 = split * 16;
    int t = threadIdx.x;
    int copg = t >> 5;                     // 0..7
    int pxg = t & 31;
    int py = pxg >> 1;                     // 0..15
    int pxl0 = (pxg & 1) * 8;              // 0 or 8

    __shared__ __align__(16) float pt[67 * 69];
    __shared__ __align__(16) float wl[48 * 68 + 64];

    float acc[8][8];
    #pragma unroll
    for (int o = 0; o < 8; ++o)
        #pragma unroll
        for (int j = 0; j < 8; ++j) acc[o][j] = 0.f;

    const InT* inb = in + (size_t)img * 1048576;

    for (int ci = 0; ci < 16; ++ci) {
        int cig = ci0 + ci;
        __syncthreads();
        for (int i = t; i < 4489; i += 256) {
            int r = i / 67, c = i - r * 67;
            int ih = r - 2, iw = c - 2;
            float v = 0.f;
            if ((unsigned)ih < 64u && (unsigned)iw < 64u)
                v = toF(inb[cig * 4096 + ih * 64 + iw]);
            pt[r * 69 + c] = v;
        }
        for (int i = t; i < 3136; i += 256) {
            int co = i / 49, tap = i - co * 49;
            wl[tap * 68 + co] = w[(size_t)(co0 + co) * 12544 + cig * 49 + tap];
        }
        __syncthreads();
        #pragma unroll
        for (int kh = 0; kh < 7; ++kh) {
            #pragma unroll
            for (int kw = 0; kw < 7; ++kw) {
                int tap = kh * 7 + kw;
                float4 w0 = *(const float4*)&wl[tap * 68 + copg * 8];
                float4 w1 = *(const float4*)&wl[tap * 68 + copg * 8 + 4];
                float wv[8] = {w0.x, w0.y, w0.z, w0.w, w1.x, w1.y, w1.z, w1.w};
                float pv[8];
                #pragma unroll
                for (int j = 0; j < 8; ++j)
                    pv[j] = pt[(py * 4 + kh) * 69 + (pxl0 + j) * 4 + kw];
                #pragma unroll
                for (int o = 0; o < 8; ++o)
                    #pragma unroll
                    for (int j = 0; j < 8; ++j)
                        acc[o][j] += wv[o] * pv[j];
            }
        }
    }
    #pragma unroll
    for (int o = 0; o < 8; ++o)
        #pragma unroll
        for (int j = 0; j < 8; ++j) {
            int co = co0 + copg * 8 + o;
            int px = py * 16 + pxl0 + j;
            atomicAdd(&p3[img * 65536 + co * 256 + px], acc[o][j]);
        }
}

// combine3: h3 = relu(bias + p3), 524288 elems, layout [img][co][16][16]
__global__ void combine3_k(const float* __restrict__ p3, const float* __restrict__ bias,
                           float* __restrict__ h3)
{
    int idx = blockIdx.x * 256 + threadIdx.x;
    int co = (idx >> 8) & 255;
    h3[idx] = fmaxf(bias[co] + p3[idx], 0.f);
}

// ===========================================================================
// conv4: 3x3 s2 p1, 256->256, 16->8. Batched. grid 512 blocks.
// ===========================================================================
__global__ void conv4_k(const float* __restrict__ in, const float* __restrict__ w,
                        const float* __restrict__ bias, float* __restrict__ out)
{
    int idx = blockIdx.x * 256 + threadIdx.x;      // 131072
    int ow = idx & 7;
    int oh = (idx >> 3) & 7;
    int co = (idx >> 6) & 255;
    int n  = idx >> 14;
    float acc = bias[co];
    const float* ib = in + (size_t)n * 65536;
    const float* wbase = w + (size_t)co * 2304;
    for (int ci = 0; ci < 256; ++ci) {
        const float* ip = ib + (size_t)ci * 256;
        const float* wp = wbase + ci * 9;
        #pragma unroll
        for (int kh = 0; kh < 3; ++kh) {
            int ih = oh * 2 - 1 + kh;
            if ((unsigned)ih < 16u) {
                #pragma unroll
                for (int kw = 0; kw < 3; ++kw) {
                    int iw = ow * 2 - 1 + kw;
                    if ((unsigned)iw < 16u)
                        acc += ip[ih * 16 + iw] * wp[kh * 3 + kw];
                }
            }
        }
    }
    out[idx] = fmaxf(acc, 0.f);
}

// residual a: t1 = conv1x3 over relu(h), 256->1024. Batched, grid 2048.
__global__ void resa_k(const float* __restrict__ h, const float* __restrict__ w,
                       float* __restrict__ t1)
{
    int idx = blockIdx.x * 256 + threadIdx.x;      // 524288
    int x = idx & 7;
    int y = (idx >> 3) & 7;
    int co = (idx >> 6) & 1023;
    int n  = idx >> 16;
    float acc = 0.f;
    const float* hb = h + (size_t)n * 16384;
    const float* wbase = w + (size_t)co * 768;
    for (int ci = 0; ci < 256; ++ci) {
        const float* row = hb + (size_t)ci * 64 + y * 8;
        const float* wp = wbase + ci * 3;
        #pragma unroll
        for (int kx = 0; kx < 3; ++kx) {
            int xx = x - 1 + kx;
            if ((unsigned)xx < 8u)
                acc += fmaxf(row[xx], 0.f) * wp[kx];
        }
    }
    t1[idx] = acc;
}

// residual b: h_new = h_old + conv1x1 over relu(t1), 1024->256. grid 512.
__global__ void resb_k(const float* __restrict__ h_old, const float* __restrict__ t1,
                       const float* __restrict__ w, float* __restrict__ h_new)
{
    int idx = blockIdx.x * 256 + threadIdx.x;      // 131072
    int x = idx & 7;
    int y = (idx >> 3) & 7;
    int co = (idx >> 6) & 255;
    int n  = idx >> 14;
    float acc = h_old[idx];
    const float* tb = t1 + (size_t)n * 65536 + y * 8 + x;
    const float* wp = w + (size_t)co * 1024;
    for (int ci = 0; ci < 1024; ++ci)
        acc += fmaxf(tb[(size_t)ci * 64], 0.f) * wp[ci];
    h_new[idx] = acc;
}

// emb norms
__global__ void embnorm_k(const float* __restrict__ emb, float* __restrict__ en)
{
    int k = blockIdx.x * 256 + threadIdx.x;        // 512
    const float* e = emb + (size_t)k * 256;
    float s = 0.f;
    for (int d = 0; d < 256; ++d) { float v = e[d]; s += v * v; }
    en[k] = s;
}

// VQ: one block per latent row (512 rows), D=256, K=512.
__global__ void vq_k(const float* __restrict__ h, const float* __restrict__ emb,
                     const float* __restrict__ en, float* __restrict__ out,
                     float* __restrict__ mse_acc, int* __restrict__ hist)
{
    int row = blockIdx.x;                          // 512 = 8*8*8
    int b = row >> 6, y = (row >> 3) & 7, xx = row & 7;
    int t = threadIdx.x;                           // 256
    __shared__ float lat[256];
    __shared__ float sdist[256];
    __shared__ int   sidx[256];

    float l = fmaxf(h[((size_t)(b * 256 + t) * 8 + y) * 8 + xx], 0.f);
    lat[t] = l;
    __syncthreads();

    float d0 = 0.f, d1 = 0.f;
    const float* e0 = emb + (size_t)t * 256;
    const float* e1 = emb + (size_t)(t + 256) * 256;
    for (int d = 0; d < 256; ++d) {
        float lv = lat[d];
        d0 += lv * e0[d];
        d1 += lv * e1[d];
    }
    d0 = en[t] - 2.f * d0;
    d1 = en[t + 256] - 2.f * d1;
    float best_d = d0; int best_i = t;
    if (d1 < best_d) { best_d = d1; best_i = t + 256; }
    sdist[t] = best_d; sidx[t] = best_i;
    __syncthreads();
    for (int s = 128; s > 0; s >>= 1) {
        if (t < s) {
            float od = sdist[t + s]; int oi = sidx[t + s];
            if (od < sdist[t] || (od == sdist[t] && oi < sidx[t])) {
                sdist[t] = od; sidx[t] = oi;
            }
        }
        __syncthreads();
    }
    int idx = sidx[0];

    float q = emb[(size_t)idx * 256 + t];
    out[((size_t)(b * 256 + t) * 8 + y) * 8 + xx] = q;
    float diff = q - lat[t];
    __syncthreads();
    sdist[t] = diff * diff;
    __syncthreads();
    for (int s = 128; s > 0; s >>= 1) {
        if (t < s) sdist[t] += sdist[t + s];
        __syncthreads();
    }
    if (t == 0) {
        atomicAdd(mse_acc, sdist[0]);
        atomicAdd(&hist[idx], 1);
    }
}

__global__ void final_k(const float* __restrict__ mse_acc, const int* __restrict__ hist,
                        float* __restrict__ out)
{
    __shared__ float sh[512];
    int t = threadIdx.x;                           // 512
    float p = (float)hist[t] / 512.f;
    sh[t] = p * logf(p + 1e-10f);
    __syncthreads();
    for (int s = 256; s > 0; s >>= 1) {
        if (t < s) sh[t] += sh[t + s];
        __syncthreads();
    }
    if (t == 0) {
        float loss = 2.f * mse_acc[0] / (512.f * 256.f);
        float perp = expf(-sh[0]);
        out[131072] = loss;
        out[131073] = perp;
    }
}

// ===========================================================================
extern "C" void kernel_launch(void* const* d_in, const int* in_sizes, int n_in,
                              void* d_out, int out_size, void* d_ws, size_t ws_size,
                              hipStream_t stream)
{
    const float* x    = (const float*)d_in[0];
    const float* w_in = (const float*)d_in[1];
    const float* b_in = (const float*)d_in[2];
    const float* w_h1 = (const float*)d_in[3];
    const float* b_h1 = (const float*)d_in[4];
    const float* w_h2 = (const float*)d_in[5];
    const float* b_h2 = (const float*)d_in[6];
    const float* w_h3 = (const float*)d_in[7];
    const float* b_h3 = (const float*)d_in[8];
    const float* r0w1 = (const float*)d_in[9];
    const float* r0w2 = (const float*)d_in[10];
    const float* r1w1 = (const float*)d_in[11];
    const float* r1w2 = (const float*)d_in[12];
    const float* emb  = (const float*)d_in[13];
    float* out = (float*)d_out;

    char* ws = (char*)d_ws;
    size_t off = 0;
    auto alloc = [&](size_t bytes) -> void* {
        void* p = ws + off;
        off += (bytes + 255) & ~(size_t)255;
        return p;
    };

    const size_t H1N = 8388608;    // 128*256*256 per image
    const size_t H2N = 8388608;    // 8 img * 256*64*64 (batched)

    // small persistent buffers
    float* h6  = (float*)alloc(131072 * 4);
    float* en  = (float*)alloc(512 * 4);
    float* mse = (float*)alloc(256);
    int*  hist = (int*)alloc(512 * 4);
    float* p2  = (float*)alloc(1048576ull * 4);    // conv2 partials, per image
    float* p3  = (float*)alloc(524288ull * 4);     // conv3 partials, batched
    float* h3  = (float*)alloc(524288ull * 4);     // [8,256,16,16]
    float* h4  = (float*)alloc(131072ull * 4);
    float* t1  = (float*)alloc(524288ull * 4);
    float* h5  = (float*)alloc(131072ull * 4);
    size_t small_end = off;

    // tiers: A = f32 h1 + f32 h2 (~79MB), B = bf16 h1 + f32 h2 (~62MB),
    //        C = bf16 h1 + bf16 h2 (~45MB)
    size_t needA = small_end + H1N * 4 + H2N * 4 + 4096;
    size_t needB = small_end + H1N * 2 + H2N * 4 + 4096;
    int tier = (ws_size >= needA) ? 0 : (ws_size >= needB) ? 1 : 2;

    void* h1  = alloc(tier == 0 ? H1N * 4 : H1N * 2);
    void* h2b = alloc(tier <= 1 ? H2N * 4 : H2N * 2);

    hipMemsetAsync(mse, 0, 4, stream);
    hipMemsetAsync(hist, 0, 512 * 4, stream);
    hipMemsetAsync(p3, 0, 524288ull * 4, stream);

    for (int n = 0; n < 8; ++n) {
        const float* xn = x + (size_t)n * 786432;
        hipMemsetAsync(p2, 0, 1048576ull * 4, stream);
        if (tier == 0) {
            float* h1f = (float*)h1;
            float* h2n = (float*)h2b + (size_t)n * 1048576;
            conv1t_k<float><<<8192, 256, 0, stream>>>(xn, w_in, b_in, h1f);
            conv2t_k<float><<<512, 256, 0, stream>>>(h1f, w_h1, p2);
            combine2_k<float><<<4096, 256, 0, stream>>>(p2, b_h1, h2n);
        } else if (tier == 1) {
            bf16* h1h = (bf16*)h1;
            float* h2n = (float*)h2b + (size_t)n * 1048576;
            conv1t_k<bf16><<<8192, 256, 0, stream>>>(xn, w_in, b_in, h1h);
            conv2t_k<bf16><<<512, 256, 0, stream>>>(h1h, w_h1, p2);
            combine2_k<float><<<4096, 256, 0, stream>>>(p2, b_h1, h2n);
        } else {
            bf16* h1h = (bf16*)h1;
            bf16* h2n = (bf16*)h2b + (size_t)n * 1048576;
            conv1t_k<bf16><<<8192, 256, 0, stream>>>(xn, w_in, b_in, h1h);
            conv2t_k<bf16><<<512, 256, 0, stream>>>(h1h, w_h1, p2);
            combine2_k<bf16><<<4096, 256, 0, stream>>>(p2, b_h1, h2n);
        }
    }

    if (tier <= 1) conv3t_k<float><<<512, 256, 0, stream>>>((const float*)h2b, w_h2, p3);
    else           conv3t_k<bf16><<<512, 256, 0, stream>>>((const bf16*)h2b, w_h2, p3);
    combine3_k<<<2048, 256, 0, stream>>>(p3, b_h2, h3);

    conv4_k<<<512, 256, 0, stream>>>(h3, w_h3, b_h3, h4);
    resa_k<<<2048, 256, 0, stream>>>(h4, r0w1, t1);
    resb_k<<<512, 256, 0, stream>>>(h4, t1, r0w2, h5);
    resa_k<<<2048, 256, 0, stream>>>(h5, r1w1, t1);
    resb_k<<<512, 256, 0, stream>>>(h5, t1, r1w2, h6);

    embnorm_k<<<2, 256, 0, stream>>>(emb, en);
    vq_k<<<512, 256, 0, stream>>>(h6, emb, en, out, mse, hist);
    final_k<<<1, 512, 0, stream>>>(mse, hist, out);
}

// Round 5
// 4353.408 us; speedup vs baseline: 8.9994x; 1.4999x over previous
//
#include <hip/hip_runtime.h>
#include <hip/hip_bf16.h>

typedef __hip_bfloat16 bf16;

__device__ __forceinline__ float toF(float v) { return v; }
__device__ __forceinline__ float toF(bf16 v) { return __bfloat162float(v); }

// ===========================================================================
// conv1: 4x4 s2 p1, Cin=3 Cout=128, 512->256. LDS input tile, 2x2 out/thread.
// bid = tx(3b) | ty(3b)<<3 | co(7b)<<6 | img<<13. Batched grid: 65536.
// ===========================================================================
template <typename OutT>
__global__ __launch_bounds__(256) void conv1t_k(const float* __restrict__ x,
        const float* __restrict__ w, const float* __restrict__ bias,
        OutT* __restrict__ out)
{
    int bid = blockIdx.x;
    int tx = bid & 7, ty = (bid >> 3) & 7, co = (bid >> 6) & 127, img = bid >> 13;
    const float* xi = x + (size_t)img * 786432;
    OutT* oi = out + (size_t)img * 8388608;
    int oh0 = ty * 32, ow0 = tx * 32;
    int t = threadIdx.x;
    int oyp = t >> 4, oxp = t & 15;

    __shared__ __align__(16) float st[66 * 68];

    float b = bias[co];
    float acc[2][2] = {{b, b}, {b, b}};
    int ihb = oh0 * 2 - 1, iwb = ow0 * 2 - 1;

    for (int ci = 0; ci < 3; ++ci) {
        __syncthreads();
        for (int i = t; i < 66 * 68; i += 256) {
            int r = i / 68, c = i - r * 68;
            float v = 0.f;
            if (c < 66) {
                int ih = ihb + r, iw = iwb + c;
                if ((unsigned)ih < 512u && (unsigned)iw < 512u)
                    v = xi[ci * 262144 + ih * 512 + iw];
            }
            st[i] = v;
        }
        __syncthreads();
        float wr[16];
        #pragma unroll
        for (int k = 0; k < 16; ++k) wr[k] = w[co * 48 + ci * 16 + k];
        #pragma unroll
        for (int rr = 0; rr < 6; ++rr) {
            int r = oyp * 4 + rr;
            int c0 = oxp * 4;
            float2 v01 = *(const float2*)&st[r * 68 + c0];
            float2 v23 = *(const float2*)&st[r * 68 + c0 + 2];
            float2 v45 = *(const float2*)&st[r * 68 + c0 + 4];
            float v[6] = {v01.x, v01.y, v23.x, v23.y, v45.x, v45.y};
            #pragma unroll
            for (int oy = 0; oy < 2; ++oy) {
                int kh = rr - oy * 2;
                if (kh >= 0 && kh < 4) {
                    #pragma unroll
                    for (int ox = 0; ox < 2; ++ox)
                        #pragma unroll
                        for (int kw = 0; kw < 4; ++kw)
                            acc[oy][ox] += v[ox * 2 + kw] * wr[kh * 4 + kw];
                }
            }
        }
    }
    #pragma unroll
    for (int oy = 0; oy < 2; ++oy)
        #pragma unroll
        for (int ox = 0; ox < 2; ++ox) {
            int oh = oh0 + oyp * 2 + oy, ow = ow0 + oxp * 2 + ox;
            oi[co * 65536 + oh * 256 + ow] = (OutT)fmaxf(acc[oy][ox], 0.f);
        }
}

// ===========================================================================
// conv2: 7x7 s4 p2, 128->256 ch, 256->64. No K-split; bias+ReLU fused.
// bid = cot(2b) | pxt(6b)<<2 | img<<8.  Batched grid: 2048 (= 8 blocks/CU).
// Block: 64co x (8x8)px. Thread: 8co x 2px (px pair {q, q+4}).
// LDS pt is phase-major: addr = ((c&3)*35 + r)*9 + (c>>2)  -> compute reads
// hit bank 4*py + q: all 32 px-lanes distinct, conflict-free.
// ===========================================================================
template <typename InT>
__global__ __launch_bounds__(256) void conv2t_k(const InT* __restrict__ in,
        const float* __restrict__ w, const float* __restrict__ bias,
        float* __restrict__ out)
{
    int bid = blockIdx.x;
    int cot = bid & 3;
    int pxt = (bid >> 2) & 63;
    int img = bid >> 8;
    int co0 = cot * 64;
    int oh0 = (pxt >> 3) * 8, ow0 = (pxt & 7) * 8;
    int t = threadIdx.x;
    int copg = t >> 5;                     // 0..7
    int pxg = t & 31;
    int py = pxg >> 2;                     // 0..7
    int q  = pxg & 3;                      // px pair {q, q+4}

    const InT* inb = in + (size_t)img * 8388608;

    __shared__ __align__(16) float pt[4 * 35 * 9];      // 1260 floats
    __shared__ __align__(16) float wl[49 * 68];         // 3332 floats

    float acc[8][2];
    #pragma unroll
    for (int o = 0; o < 8; ++o) { acc[o][0] = 0.f; acc[o][1] = 0.f; }

    int ihb = oh0 * 4 - 2, iwb = ow0 * 4 - 2;

    for (int ci = 0; ci < 128; ++ci) {
        __syncthreads();
        for (int i = t; i < 1225; i += 256) {
            int r = i / 35, c = i - r * 35;
            int ih = ihb + r, iw = iwb + c;
            float v = 0.f;
            if ((unsigned)ih < 256u && (unsigned)iw < 256u)
                v = toF(inb[ci * 65536 + ih * 256 + iw]);
            pt[((c & 3) * 35 + r) * 9 + (c >> 2)] = v;
        }
        for (int i = t; i < 3136; i += 256) {
            int co = i / 49, tap = i - co * 49;
            wl[tap * 68 + co] = w[(size_t)(co0 + co) * 6272 + ci * 49 + tap];
        }
        __syncthreads();
        #pragma unroll
        for (int kh = 0; kh < 7; ++kh) {
            #pragma unroll
            for (int kw = 0; kw < 7; ++kw) {
                int tap = kh * 7 + kw;
                float4 w0 = *(const float4*)&wl[tap * 68 + copg * 8];
                float4 w1 = *(const float4*)&wl[tap * 68 + copg * 8 + 4];
                int base = (((kw & 3) * 35) + py * 4 + kh) * 9 + (kw >> 2);
                float p0 = pt[base + q];
                float p1 = pt[base + q + 4];
                acc[0][0] += w0.x * p0; acc[0][1] += w0.x * p1;
                acc[1][0] += w0.y * p0; acc[1][1] += w0.y * p1;
                acc[2][0] += w0.z * p0; acc[2][1] += w0.z * p1;
                acc[3][0] += w0.w * p0; acc[3][1] += w0.w * p1;
                acc[4][0] += w1.x * p0; acc[4][1] += w1.x * p1;
                acc[5][0] += w1.y * p0; acc[5][1] += w1.y * p1;
                acc[6][0] += w1.z * p0; acc[6][1] += w1.z * p1;
                acc[7][0] += w1.w * p0; acc[7][1] += w1.w * p1;
            }
        }
    }
    float* ob = out + (size_t)img * 1048576;
    #pragma unroll
    for (int o = 0; o < 8; ++o) {
        int co = co0 + copg * 8 + o;
        float b = bias[co];
        int oh = oh0 + py;
        ob[co * 4096 + oh * 64 + ow0 + q]     = fmaxf(b + acc[o][0], 0.f);
        ob[co * 4096 + oh * 64 + ow0 + q + 4] = fmaxf(b + acc[o][1], 0.f);
    }
}

// ===========================================================================
// conv3 tiled: 7x7 s4 p2, 256->256 ch, 64->16. Batched imgs, K-split 16,
// atomic f32 partials. grid: 4 cot * 8 img * 16 split = 512 blocks.
// ===========================================================================
__global__ __launch_bounds__(256) void conv3t_k(const float* __restrict__ in,
        const float* __restrict__ w, float* __restrict__ p3)
{
    int bid = blockIdx.x;
    int cot = bid & 3;
    int img = (bid >> 2) & 7;
    int split = bid >> 5;                  // 0..15
    int co0 = cot * 64;
    int ci0 = split * 16;
    int t = threadIdx.x;
    int copg = t >> 5;                     // 0..7
    int pxg = t & 31;
    int py = pxg >> 1;                     // 0..15
    int pxl0 = (pxg & 1) * 8;              // 0 or 8

    __shared__ __align__(16) float pt[67 * 69];
    __shared__ __align__(16) float wl[49 * 68];

    float acc[8][8];
    #pragma unroll
    for (int o = 0; o < 8; ++o)
        #pragma unroll
        for (int j = 0; j < 8; ++j) acc[o][j] = 0.f;

    const float* inb = in + (size_t)img * 1048576;

    for (int ci = 0; ci < 16; ++ci) {
        int cig = ci0 + ci;
        __syncthreads();
        for (int i = t; i < 4489; i += 256) {
            int r = i / 67, c = i - r * 67;
            int ih = r - 2, iw = c - 2;
            float v = 0.f;
            if ((unsigned)ih < 64u && (unsigned)iw < 64u)
                v = inb[cig * 4096 + ih * 64 + iw];
            pt[r * 69 + c] = v;
        }
        for (int i = t; i < 3136; i += 256) {
            int co = i / 49, tap = i - co * 49;
            wl[tap * 68 + co] = w[(size_t)(co0 + co) * 12544 + cig * 49 + tap];
        }
        __syncthreads();
        #pragma unroll
        for (int kh = 0; kh < 7; ++kh) {
            #pragma unroll
            for (int kw = 0; kw < 7; ++kw) {
                int tap = kh * 7 + kw;
                float4 w0 = *(const float4*)&wl[tap * 68 + copg * 8];
                float4 w1 = *(const float4*)&wl[tap * 68 + copg * 8 + 4];
                float wv[8] = {w0.x, w0.y, w0.z, w0.w, w1.x, w1.y, w1.z, w1.w};
                float pv[8];
                #pragma unroll
                for (int j = 0; j < 8; ++j)
                    pv[j] = pt[(py * 4 + kh) * 69 + (pxl0 + j) * 4 + kw];
                #pragma unroll
                for (int o = 0; o < 8; ++o)
                    #pragma unroll
                    for (int j = 0; j < 8; ++j)
                        acc[o][j] += wv[o] * pv[j];
            }
        }
    }
    #pragma unroll
    for (int o = 0; o < 8; ++o)
        #pragma unroll
        for (int j = 0; j < 8; ++j) {
            int co = co0 + copg * 8 + o;
            int px = py * 16 + pxl0 + j;
            atomicAdd(&p3[img * 65536 + co * 256 + px], acc[o][j]);
        }
}

// combine3: h3 = relu(bias + p3), 524288 elems
__global__ void combine3_k(const float* __restrict__ p3, const float* __restrict__ bias,
                           float* __restrict__ h3)
{
    int idx = blockIdx.x * 256 + threadIdx.x;
    int co = (idx >> 8) & 255;
    h3[idx] = fmaxf(bias[co] + p3[idx], 0.f);
}

// conv4: 3x3 s2 p1, 256->256, 16->8. Batched. grid 512.
__global__ void conv4_k(const float* __restrict__ in, const float* __restrict__ w,
                        const float* __restrict__ bias, float* __restrict__ out)
{
    int idx = blockIdx.x * 256 + threadIdx.x;      // 131072
    int ow = idx & 7;
    int oh = (idx >> 3) & 7;
    int co = (idx >> 6) & 255;
    int n  = idx >> 14;
    float acc = bias[co];
    const float* ib = in + (size_t)n * 65536;
    const float* wbase = w + (size_t)co * 2304;
    for (int ci = 0; ci < 256; ++ci) {
        const float* ip = ib + (size_t)ci * 256;
        const float* wp = wbase + ci * 9;
        #pragma unroll
        for (int kh = 0; kh < 3; ++kh) {
            int ih = oh * 2 - 1 + kh;
            if ((unsigned)ih < 16u) {
                #pragma unroll
                for (int kw = 0; kw < 3; ++kw) {
                    int iw = ow * 2 - 1 + kw;
                    if ((unsigned)iw < 16u)
                        acc += ip[ih * 16 + iw] * wp[kh * 3 + kw];
                }
            }
        }
    }
    out[idx] = fmaxf(acc, 0.f);
}

// residual a: t1 = conv1x3 over relu(h), 256->1024. grid 2048.
__global__ void resa_k(const float* __restrict__ h, const float* __restrict__ w,
                       float* __restrict__ t1)
{
    int idx = blockIdx.x * 256 + threadIdx.x;      // 524288
    int x = idx & 7;
    int y = (idx >> 3) & 7;
    int co = (idx >> 6) & 1023;
    int n  = idx >> 16;
    float acc = 0.f;
    const float* hb = h + (size_t)n * 16384;
    const float* wbase = w + (size_t)co * 768;
    for (int ci = 0; ci < 256; ++ci) {
        const float* row = hb + (size_t)ci * 64 + y * 8;
        const float* wp = wbase + ci * 3;
        #pragma unroll
        for (int kx = 0; kx < 3; ++kx) {
            int xx = x - 1 + kx;
            if ((unsigned)xx < 8u)
                acc += fmaxf(row[xx], 0.f) * wp[kx];
        }
    }
    t1[idx] = acc;
}

// residual b: h_new = h_old + conv1x1 over relu(t1), 1024->256. grid 512.
__global__ void resb_k(const float* __restrict__ h_old, const float* __restrict__ t1,
                       const float* __restrict__ w, float* __restrict__ h_new)
{
    int idx = blockIdx.x * 256 + threadIdx.x;      // 131072
    int x = idx & 7;
    int y = (idx >> 3) & 7;
    int co = (idx >> 6) & 255;
    int n  = idx >> 14;
    float acc = h_old[idx];
    const float* tb = t1 + (size_t)n * 65536 + y * 8 + x;
    const float* wp = w + (size_t)co * 1024;
    for (int ci = 0; ci < 1024; ++ci)
        acc += fmaxf(tb[(size_t)ci * 64], 0.f) * wp[ci];
    h_new[idx] = acc;
}

// emb norms
__global__ void embnorm_k(const float* __restrict__ emb, float* __restrict__ en)
{
    int k = blockIdx.x * 256 + threadIdx.x;        // 512
    const float* e = emb + (size_t)k * 256;
    float s = 0.f;
    for (int d = 0; d < 256; ++d) { float v = e[d]; s += v * v; }
    en[k] = s;
}

// VQ: one block per latent row (512 rows), D=256, K=512.
__global__ void vq_k(const float* __restrict__ h, const float* __restrict__ emb,
                     const float* __restrict__ en, float* __restrict__ out,
                     float* __restrict__ mse_acc, int* __restrict__ hist)
{
    int row = blockIdx.x;                          // 512 = 8*8*8
    int b = row >> 6, y = (row >> 3) & 7, xx = row & 7;
    int t = threadIdx.x;                           // 256
    __shared__ float lat[256];
    __shared__ float sdist[256];
    __shared__ int   sidx[256];

    float l = fmaxf(h[((size_t)(b * 256 + t) * 8 + y) * 8 + xx], 0.f);
    lat[t] = l;
    __syncthreads();

    float d0 = 0.f, d1 = 0.f;
    const float* e0 = emb + (size_t)t * 256;
    const float* e1 = emb + (size_t)(t + 256) * 256;
    for (int d = 0; d < 256; ++d) {
        float lv = lat[d];
        d0 += lv * e0[d];
        d1 += lv * e1[d];
    }
    d0 = en[t] - 2.f * d0;
    d1 = en[t + 256] - 2.f * d1;
    float best_d = d0; int best_i = t;
    if (d1 < best_d) { best_d = d1; best_i = t + 256; }
    sdist[t] = best_d; sidx[t] = best_i;
    __syncthreads();
    for (int s = 128; s > 0; s >>= 1) {
        if (t < s) {
            float od = sdist[t + s]; int oi = sidx[t + s];
            if (od < sdist[t] || (od == sdist[t] && oi < sidx[t])) {
                sdist[t] = od; sidx[t] = oi;
            }
        }
        __syncthreads();
    }
    int idx = sidx[0];

    float q = emb[(size_t)idx * 256 + t];
    out[((size_t)(b * 256 + t) * 8 + y) * 8 + xx] = q;
    float diff = q - lat[t];
    __syncthreads();
    sdist[t] = diff * diff;
    __syncthreads();
    for (int s = 128; s > 0; s >>= 1) {
        if (t < s) sdist[t] += sdist[t + s];
        __syncthreads();
    }
    if (t == 0) {
        atomicAdd(mse_acc, sdist[0]);
        atomicAdd(&hist[idx], 1);
    }
}

__global__ void final_k(const float* __restrict__ mse_acc, const int* __restrict__ hist,
                        float* __restrict__ out)
{
    __shared__ float sh[512];
    int t = threadIdx.x;                           // 512
    float p = (float)hist[t] / 512.f;
    sh[t] = p * logf(p + 1e-10f);
    __syncthreads();
    for (int s = 256; s > 0; s >>= 1) {
        if (t < s) sh[t] += sh[t + s];
        __syncthreads();
    }
    if (t == 0) {
        float loss = 2.f * mse_acc[0] / (512.f * 256.f);
        float perp = expf(-sh[0]);
        out[131072] = loss;
        out[131073] = perp;
    }
}

// ===========================================================================
extern "C" void kernel_launch(void* const* d_in, const int* in_sizes, int n_in,
                              void* d_out, int out_size, void* d_ws, size_t ws_size,
                              hipStream_t stream)
{
    const float* x    = (const float*)d_in[0];
    const float* w_in = (const float*)d_in[1];
    const float* b_in = (const float*)d_in[2];
    const float* w_h1 = (const float*)d_in[3];
    const float* b_h1 = (const float*)d_in[4];
    const float* w_h2 = (const float*)d_in[5];
    const float* b_h2 = (const float*)d_in[6];
    const float* w_h3 = (const float*)d_in[7];
    const float* b_h3 = (const float*)d_in[8];
    const float* r0w1 = (const float*)d_in[9];
    const float* r0w2 = (const float*)d_in[10];
    const float* r1w1 = (const float*)d_in[11];
    const float* r1w2 = (const float*)d_in[12];
    const float* emb  = (const float*)d_in[13];
    float* out = (float*)d_out;

    char* ws = (char*)d_ws;
    size_t off = 0;
    auto alloc = [&](size_t bytes) -> void* {
        void* p = ws + off;
        off += (bytes + 255) & ~(size_t)255;
        return p;
    };

    // small persistent buffers (~7 MB)
    float* h6  = (float*)alloc(131072 * 4);
    float* en  = (float*)alloc(512 * 4);
    float* mse = (float*)alloc(256);
    int*  hist = (int*)alloc(512 * 4);
    float* p3  = (float*)alloc(524288ull * 4);
    float* h3  = (float*)alloc(524288ull * 4);
    float* h4  = (float*)alloc(131072ull * 4);
    float* t1  = (float*)alloc(524288ull * 4);
    float* h5  = (float*)alloc(131072ull * 4);
    // h2 always f32, full batch [8,256,64,64] = 33.5 MB
    float* h2b = (float*)alloc(8388608ull * 4);
    size_t base_end = off;

    const size_t H1I = 8388608;    // per-image h1 elems
    // tiers for h1: A = f32 batched (268MB), B = bf16 batched (134MB),
    //               C = f32 per-image (33.5MB), D = bf16 per-image (16.8MB)
    size_t needA = base_end + H1I * 8 * 4 + 4096;
    size_t needB = base_end + H1I * 8 * 2 + 4096;
    size_t needC = base_end + H1I * 4 + 4096;
    int tier = (ws_size >= needA) ? 0 : (ws_size >= needB) ? 1
             : (ws_size >= needC) ? 2 : 3;

    void* h1 = alloc(tier == 0 ? H1I * 8 * 4 : tier == 1 ? H1I * 8 * 2
                   : tier == 2 ? H1I * 4     : H1I * 2);

    hipMemsetAsync(mse, 0, 4, stream);
    hipMemsetAsync(hist, 0, 512 * 4, stream);
    hipMemsetAsync(p3, 0, 524288ull * 4, stream);

    if (tier == 0) {
        conv1t_k<float><<<65536, 256, 0, stream>>>(x, w_in, b_in, (float*)h1);
        conv2t_k<float><<<2048, 256, 0, stream>>>((const float*)h1, w_h1, b_h1, h2b);
    } else if (tier == 1) {
        conv1t_k<bf16><<<65536, 256, 0, stream>>>(x, w_in, b_in, (bf16*)h1);
        conv2t_k<bf16><<<2048, 256, 0, stream>>>((const bf16*)h1, w_h1, b_h1, h2b);
    } else if (tier == 2) {
        for (int n = 0; n < 8; ++n) {
            conv1t_k<float><<<8192, 256, 0, stream>>>(x + (size_t)n * 786432, w_in, b_in, (float*)h1);
            conv2t_k<float><<<256, 256, 0, stream>>>((const float*)h1, w_h1, b_h1, h2b + (size_t)n * 1048576);
        }
    } else {
        for (int n = 0; n < 8; ++n) {
            conv1t_k<bf16><<<8192, 256, 0, stream>>>(x + (size_t)n * 786432, w_in, b_in, (bf16*)h1);
            conv2t_k<bf16><<<256, 256, 0, stream>>>((const bf16*)h1, w_h1, b_h1, h2b + (size_t)n * 1048576);
        }
    }

    conv3t_k<<<512, 256, 0, stream>>>(h2b, w_h2, p3);
    combine3_k<<<2048, 256, 0, stream>>>(p3, b_h2, h3);

    conv4_k<<<512, 256, 0, stream>>>(h3, w_h3, b_h3, h4);
    resa_k<<<2048, 256, 0, stream>>>(h4, r0w1, t1);
    resb_k<<<512, 256, 0, stream>>>(h4, t1, r0w2, h5);
    resa_k<<<2048, 256, 0, stream>>>(h5, r1w1, t1);
    resb_k<<<512, 256, 0, stream>>>(h5, t1, r1w2, h6);

    embnorm_k<<<2, 256, 0, stream>>>(emb, en);
    vq_k<<<512, 256, 0, stream>>>(h6, emb, en, out, mse, hist);
    final_k<<<1, 512, 0, stream>>>(mse, hist, out);
}

// Round 6
// 1730.387 us; speedup vs baseline: 22.6412x; 2.5159x over previous
//
#include <hip/hip_runtime.h>
#include <hip/hip_bf16.h>

typedef __hip_bfloat16 bf16;
typedef __attribute__((ext_vector_type(4))) float f32x4;
typedef __attribute__((ext_vector_type(8))) short short8;

// ===========================================================================
// conv1 -> NHWC bf16: 4x4 s2 p1, Cin=3 Cout=128, 512->256.
// Block: 8x8 px tile x 128 co. Thread: 1 px x 32 co (co = cog*32 + u4*4 + e).
// Writes h1T[(oh*256+ow)*128 + co] -- 64B contiguous per thread.
// grid: 1024 pxtiles * img
// ===========================================================================
__global__ __launch_bounds__(256) void conv1n_k(const float* __restrict__ x,
        const float* __restrict__ w, const float* __restrict__ bias,
        bf16* __restrict__ h1T)
{
    int bid = blockIdx.x;
    int pxt = bid & 1023, img = bid >> 10;
    int oh0 = (pxt >> 5) * 8, ow0 = (pxt & 31) * 8;
    const float* xi = x + (size_t)img * 786432;
    bf16* oT = h1T + (size_t)img * 8388608;
    int t = threadIdx.x;
    int px = t >> 2, cog = t & 3;
    int py = px >> 3, qx = px & 7;

    __shared__ float pt1[3 * 18 * 18];          // [ci][r][c], stride 18
    __shared__ float wl[6144];                  // [u4][48 tapidx][4 cog][4 e]

    for (int i = t; i < 6144; i += 256) {
        int u4b = i / 768; int r1 = i - u4b * 768;
        int tapidx = r1 >> 4; int r2 = r1 & 15;
        int cog2 = r2 >> 2, e = r2 & 3;
        int co = cog2 * 32 + u4b * 4 + e;
        wl[i] = w[co * 48 + tapidx];
    }
    int ihb = oh0 * 2 - 1, iwb = ow0 * 2 - 1;
    for (int i = t; i < 972; i += 256) {
        int ci = i / 324; int r1 = i - ci * 324;
        int r = r1 / 18, c = r1 - r * 18;
        int ih = ihb + r, iw = iwb + c;
        float v = 0.f;
        if ((unsigned)ih < 512u && (unsigned)iw < 512u)
            v = xi[ci * 262144 + ih * 512 + iw];
        pt1[i] = v;
    }
    __syncthreads();

    float acc[32];
    #pragma unroll
    for (int i = 0; i < 32; ++i) acc[i] = 0.f;

    #pragma unroll
    for (int ci = 0; ci < 3; ++ci)
        #pragma unroll
        for (int kh = 0; kh < 4; ++kh)
            #pragma unroll
            for (int kw = 0; kw < 4; ++kw) {
                float pv = pt1[ci * 324 + (2 * py + kh) * 18 + 2 * qx + kw];
                int tapidx = ci * 16 + kh * 4 + kw;
                #pragma unroll
                for (int u4 = 0; u4 < 8; ++u4) {
                    f32x4 wv = *(const f32x4*)&wl[((u4 * 48 + tapidx) * 4 + cog) * 4];
                    acc[u4 * 4 + 0] += pv * wv[0];
                    acc[u4 * 4 + 1] += pv * wv[1];
                    acc[u4 * 4 + 2] += pv * wv[2];
                    acc[u4 * 4 + 3] += pv * wv[3];
                }
            }

    int co0 = cog * 32;
    size_t base = ((size_t)(oh0 + py) * 256 + (ow0 + qx)) * 128 + co0;
    #pragma unroll
    for (int i = 0; i < 16; ++i) {
        __hip_bfloat162 pr;
        pr.x = __float2bfloat16(fmaxf(bias[co0 + 2 * i] + acc[2 * i], 0.f));
        pr.y = __float2bfloat16(fmaxf(bias[co0 + 2 * i + 1] + acc[2 * i + 1], 0.f));
        *(__hip_bfloat162*)(oT + base + 2 * i) = pr;
    }
}

// ===========================================================================
// weight pack for 7x7 convs: wpack[tap 0..49][ci>>3][co 0..255][ci&7] bf16,
// tap 49 = zeros (K padding so kstep = 2 taps x 16 ci divides evenly).
// ===========================================================================
template <int CI>
__global__ void wpack_k(const float* __restrict__ w, bf16* __restrict__ wp)
{
    int i = blockIdx.x * 256 + threadIdx.x;     // 50*CI*256 total
    int cil = i & 7; int co = (i >> 3) & 255; int r = i >> 11;
    int cib8 = r % (CI / 8); int tap = r / (CI / 8);
    float v = 0.f;
    if (tap < 49) v = w[co * (CI * 49) + (cib8 * 8 + cil) * 49 + tap];
    wp[i] = __float2bfloat16(v);
}

// ===========================================================================
// implicit-GEMM MFMA conv, 7x7 s4 p2 (conv2: IH=256,OH=64,CI=128;
// conv3: IH=64,OH=16,CI=256). M=co(256), N=px, K=CI*49.
// Block: 64co x 64px, 4 waves = 2co-sub32 x 2px-sub32, each wave 4 MFMA tiles.
// K-loop: chunks of 16 ci; per chunk stage 35x35x16 bf16 patch in LDS
// (ushort stride 18 -> B-frag b32 reads ~2-way conflicts); per kstep =
// 2 taps x 16 ci. A-frags 16B direct from L2-resident wpack.
// Verified layouts: A[m=lane&15][k=quad*8+j]; C col=lane&15,row=quad*4+reg.
// ===========================================================================
template <int IH, int OH, int CI, bool WRITE_T>
__global__ __launch_bounds__(256) void conv_mfma_k(
        const bf16* __restrict__ inT, const bf16* __restrict__ wpack,
        const float* __restrict__ bias, float* __restrict__ outN,
        bf16* __restrict__ outT)
{
    constexpr int TPD = OH / 8;
    constexpr int CHUNKS = CI / 16;
    constexpr int CIB8 = CI / 8;
    int bid = blockIdx.x;
    int cot = bid & 3;
    int rest = bid >> 2;
    int pxt = rest % (TPD * TPD);
    int img = rest / (TPD * TPD);
    int co0 = cot * 64;
    int oh0 = (pxt / TPD) * 8, ow0 = (pxt % TPD) * 8;

    int t = threadIdx.x;
    int wave = t >> 6, lane = t & 63;
    int quad = lane >> 4, l15 = lane & 15;
    int wco = wave & 1, wpx = wave >> 1;
    int oc8 = (quad & 1) * 8;
    int tquad = quad >> 1;

    const bf16* inb = inT + (size_t)img * ((size_t)IH * IH * CI);

    __shared__ ushort pt[35 * 35 * 18];          // 44.1 KB

    f32x4 zero = {0.f, 0.f, 0.f, 0.f};
    f32x4 acc[2][2] = {{zero, zero}, {zero, zero}};

    int ihb = oh0 * 4 - 2, iwb = ow0 * 4 - 2;
    int pxA = wpx * 32 + l15;
    int pxB = pxA + 16;
    int pyA = pxA >> 3, qxA = pxA & 7;
    int pyB = pxB >> 3, qxB = pxB & 7;

    for (int ch = 0; ch < CHUNKS; ++ch) {
        __syncthreads();
        int CI0 = ch * 16;
        for (int i = t; i < 9800; i += 256) {
            int pos = i >> 3;
            int c2 = (i & 7) << 1;
            int r = pos / 35, c = pos - r * 35;
            int ih = ihb + r, iw = iwb + c;
            uint v = 0;
            if ((unsigned)ih < (unsigned)IH && (unsigned)iw < (unsigned)IH)
                v = *(const uint*)(inb + ((size_t)(ih * IH + iw) * CI + CI0 + c2));
            *(uint*)&pt[pos * 18 + c2] = v;
        }
        __syncthreads();

        for (int tp = 0; tp < 25; ++tp) {
            int tap = 2 * tp + tquad;            // tap 49 has zero A (pad)
            const bf16* wbase = wpack +
                (size_t)((tap * CIB8 + ch * 2 + (quad & 1)) * 256) * 8;
            short8 a0 = *(const short8*)(wbase + (size_t)(co0 + wco * 32 + l15) * 8);
            short8 a1 = *(const short8*)(wbase + (size_t)(co0 + wco * 32 + 16 + l15) * 8);

            int tapc = min(tap, 48);             // clamp B pos (A=0 kills pad)
            int kh = tapc / 7, kw = tapc - kh * 7;
            int posA = (pyA * 4 + kh) * 35 + qxA * 4 + kw;
            int posB = (pyB * 4 + kh) * 35 + qxB * 4 + kw;
            union { short8 v; uint u[4]; } b0, b1;
            const ushort* pA = &pt[posA * 18 + oc8];
            const ushort* pB = &pt[posB * 18 + oc8];
            b0.u[0] = *(const uint*)(pA);     b0.u[1] = *(const uint*)(pA + 2);
            b0.u[2] = *(const uint*)(pA + 4); b0.u[3] = *(const uint*)(pA + 6);
            b1.u[0] = *(const uint*)(pB);     b1.u[1] = *(const uint*)(pB + 2);
            b1.u[2] = *(const uint*)(pB + 4); b1.u[3] = *(const uint*)(pB + 6);

            acc[0][0] = __builtin_amdgcn_mfma_f32_16x16x32_bf16(a0, b0.v, acc[0][0], 0, 0, 0);
            acc[0][1] = __builtin_amdgcn_mfma_f32_16x16x32_bf16(a0, b1.v, acc[0][1], 0, 0, 0);
            acc[1][0] = __builtin_amdgcn_mfma_f32_16x16x32_bf16(a1, b0.v, acc[1][0], 0, 0, 0);
            acc[1][1] = __builtin_amdgcn_mfma_f32_16x16x32_bf16(a1, b1.v, acc[1][1], 0, 0, 0);
        }
    }

    #pragma unroll
    for (int cs = 0; cs < 2; ++cs) {
        int cobase = co0 + wco * 32 + cs * 16 + quad * 4;
        #pragma unroll
        for (int ps = 0; ps < 2; ++ps) {
            int px = wpx * 32 + ps * 16 + l15;
            int oh = oh0 + (px >> 3), ow = ow0 + (px & 7);
            #pragma unroll
            for (int r = 0; r < 4; ++r) {
                int co = cobase + r;
                float v = fmaxf(bias[co] + acc[cs][ps][r], 0.f);
                if (WRITE_T)
                    outT[(size_t)img * (OH * OH * 256) + (size_t)(oh * OH + ow) * 256 + co]
                        = __float2bfloat16(v);
                else
                    outN[(size_t)img * (OH * OH * 256) + (size_t)co * (OH * OH) + oh * OH + ow]
                        = v;
            }
        }
    }
}

// ===========================================================================
// conv4: 3x3 s2 p1, 256->256, 16->8 (f32 NCHW). grid 512.
// ===========================================================================
__global__ void conv4_k(const float* __restrict__ in, const float* __restrict__ w,
                        const float* __restrict__ bias, float* __restrict__ out)
{
    int idx = blockIdx.x * 256 + threadIdx.x;      // 131072
    int ow = idx & 7;
    int oh = (idx >> 3) & 7;
    int co = (idx >> 6) & 255;
    int n  = idx >> 14;
    float acc = bias[co];
    const float* ib = in + (size_t)n * 65536;
    const float* wbase = w + (size_t)co * 2304;
    for (int ci = 0; ci < 256; ++ci) {
        const float* ip = ib + (size_t)ci * 256;
        const float* wp = wbase + ci * 9;
        #pragma unroll
        for (int kh = 0; kh < 3; ++kh) {
            int ih = oh * 2 - 1 + kh;
            if ((unsigned)ih < 16u) {
                #pragma unroll
                for (int kw = 0; kw < 3; ++kw) {
                    int iw = ow * 2 - 1 + kw;
                    if ((unsigned)iw < 16u)
                        acc += ip[ih * 16 + iw] * wp[kh * 3 + kw];
                }
            }
        }
    }
    out[idx] = fmaxf(acc, 0.f);
}

// residual a: t1 = conv1x3 over relu(h), 256->1024. grid 2048.
__global__ void resa_k(const float* __restrict__ h, const float* __restrict__ w,
                       float* __restrict__ t1)
{
    int idx = blockIdx.x * 256 + threadIdx.x;      // 524288
    int x = idx & 7;
    int y = (idx >> 3) & 7;
    int co = (idx >> 6) & 1023;
    int n  = idx >> 16;
    float acc = 0.f;
    const float* hb = h + (size_t)n * 16384;
    const float* wbase = w + (size_t)co * 768;
    for (int ci = 0; ci < 256; ++ci) {
        const float* row = hb + (size_t)ci * 64 + y * 8;
        const float* wp = wbase + ci * 3;
        #pragma unroll
        for (int kx = 0; kx < 3; ++kx) {
            int xx = x - 1 + kx;
            if ((unsigned)xx < 8u)
                acc += fmaxf(row[xx], 0.f) * wp[kx];
        }
    }
    t1[idx] = acc;
}

// residual b: h_new = h_old + conv1x1 over relu(t1), 1024->256. grid 512.
__global__ void resb_k(const float* __restrict__ h_old, const float* __restrict__ t1,
                       const float* __restrict__ w, float* __restrict__ h_new)
{
    int idx = blockIdx.x * 256 + threadIdx.x;      // 131072
    int x = idx & 7;
    int y = (idx >> 3) & 7;
    int co = (idx >> 6) & 255;
    int n  = idx >> 14;
    float acc = h_old[idx];
    const float* tb = t1 + (size_t)n * 65536 + y * 8 + x;
    const float* wp = w + (size_t)co * 1024;
    for (int ci = 0; ci < 1024; ++ci)
        acc += fmaxf(tb[(size_t)ci * 64], 0.f) * wp[ci];
    h_new[idx] = acc;
}

__global__ void embnorm_k(const float* __restrict__ emb, float* __restrict__ en)
{
    int k = blockIdx.x * 256 + threadIdx.x;        // 512
    const float* e = emb + (size_t)k * 256;
    float s = 0.f;
    for (int d = 0; d < 256; ++d) { float v = e[d]; s += v * v; }
    en[k] = s;
}

// VQ: one block per latent row (512 rows), D=256, K=512.
__global__ void vq_k(const float* __restrict__ h, const float* __restrict__ emb,
                     const float* __restrict__ en, float* __restrict__ out,
                     float* __restrict__ mse_acc, int* __restrict__ hist)
{
    int row = blockIdx.x;                          // 512 = 8*8*8
    int b = row >> 6, y = (row >> 3) & 7, xx = row & 7;
    int t = threadIdx.x;                           // 256
    __shared__ float lat[256];
    __shared__ float sdist[256];
    __shared__ int   sidx[256];

    float l = fmaxf(h[((size_t)(b * 256 + t) * 8 + y) * 8 + xx], 0.f);
    lat[t] = l;
    __syncthreads();

    float d0 = 0.f, d1 = 0.f;
    const float* e0 = emb + (size_t)t * 256;
    const float* e1 = emb + (size_t)(t + 256) * 256;
    for (int d = 0; d < 256; ++d) {
        float lv = lat[d];
        d0 += lv * e0[d];
        d1 += lv * e1[d];
    }
    d0 = en[t] - 2.f * d0;
    d1 = en[t + 256] - 2.f * d1;
    float best_d = d0; int best_i = t;
    if (d1 < best_d) { best_d = d1; best_i = t + 256; }
    sdist[t] = best_d; sidx[t] = best_i;
    __syncthreads();
    for (int s = 128; s > 0; s >>= 1) {
        if (t < s) {
            float od = sdist[t + s]; int oi = sidx[t + s];
            if (od < sdist[t] || (od == sdist[t] && oi < sidx[t])) {
                sdist[t] = od; sidx[t] = oi;
            }
        }
        __syncthreads();
    }
    int idx = sidx[0];

    float q = emb[(size_t)idx * 256 + t];
    out[((size_t)(b * 256 + t) * 8 + y) * 8 + xx] = q;
    float diff = q - lat[t];
    __syncthreads();
    sdist[t] = diff * diff;
    __syncthreads();
    for (int s = 128; s > 0; s >>= 1) {
        if (t < s) sdist[t] += sdist[t + s];
        __syncthreads();
    }
    if (t == 0) {
        atomicAdd(mse_acc, sdist[0]);
        atomicAdd(&hist[idx], 1);
    }
}

__global__ void final_k(const float* __restrict__ mse_acc, const int* __restrict__ hist,
                        float* __restrict__ out)
{
    __shared__ float sh[512];
    int t = threadIdx.x;                           // 512
    float p = (float)hist[t] / 512.f;
    sh[t] = p * logf(p + 1e-10f);
    __syncthreads();
    for (int s = 256; s > 0; s >>= 1) {
        if (t < s) sh[t] += sh[t + s];
        __syncthreads();
    }
    if (t == 0) {
        float loss = 2.f * mse_acc[0] / (512.f * 256.f);
        float perp = expf(-sh[0]);
        out[131072] = loss;
        out[131073] = perp;
    }
}

// ===========================================================================
extern "C" void kernel_launch(void* const* d_in, const int* in_sizes, int n_in,
                              void* d_out, int out_size, void* d_ws, size_t ws_size,
                              hipStream_t stream)
{
    const float* x    = (const float*)d_in[0];
    const float* w_in = (const float*)d_in[1];
    const float* b_in = (const float*)d_in[2];
    const float* w_h1 = (const float*)d_in[3];
    const float* b_h1 = (const float*)d_in[4];
    const float* w_h2 = (const float*)d_in[5];
    const float* b_h2 = (const float*)d_in[6];
    const float* w_h3 = (const float*)d_in[7];
    const float* b_h3 = (const float*)d_in[8];
    const float* r0w1 = (const float*)d_in[9];
    const float* r0w2 = (const float*)d_in[10];
    const float* r1w1 = (const float*)d_in[11];
    const float* r1w2 = (const float*)d_in[12];
    const float* emb  = (const float*)d_in[13];
    float* out = (float*)d_out;

    char* ws = (char*)d_ws;
    size_t off = 0;
    auto alloc = [&](size_t bytes) -> void* {
        void* p = ws + off;
        off += (bytes + 255) & ~(size_t)255;
        return p;
    };

    float* h6  = (float*)alloc(131072ull * 4);
    float* en  = (float*)alloc(512 * 4);
    float* mse = (float*)alloc(256);
    int*  hist = (int*)alloc(512 * 4);
    float* h3  = (float*)alloc(524288ull * 4);     // [8,256,16,16] NCHW f32
    float* h4  = (float*)alloc(131072ull * 4);
    float* t1  = (float*)alloc(524288ull * 4);
    float* h5  = (float*)alloc(131072ull * 4);
    bf16* wpack2 = (bf16*)alloc(1638400ull * 2);   // 50*16*256*8
    bf16* wpack3 = (bf16*)alloc(3276800ull * 2);   // 50*32*256*8
    bf16* h2T  = (bf16*)alloc(8388608ull * 2);     // [8,64,64,256] NHWC bf16
    size_t base_end = off;

    const size_t H1TI = 8388608;                   // per-image h1T elems
    size_t needFull = base_end + H1TI * 8 * 2 + 4096;   // ~167 MB total
    bool full = ws_size >= needFull;
    bf16* h1T = (bf16*)alloc(full ? H1TI * 8 * 2 : H1TI * 2);

    hipMemsetAsync(mse, 0, 4, stream);
    hipMemsetAsync(hist, 0, 512 * 4, stream);

    wpack_k<128><<<6400, 256, 0, stream>>>(w_h1, wpack2);
    wpack_k<256><<<12800, 256, 0, stream>>>(w_h2, wpack3);

    if (full) {
        conv1n_k<<<8192, 256, 0, stream>>>(x, w_in, b_in, h1T);
        conv_mfma_k<256, 64, 128, true><<<2048, 256, 0, stream>>>(
            h1T, wpack2, b_h1, nullptr, h2T);
    } else {
        for (int n = 0; n < 8; ++n) {
            conv1n_k<<<1024, 256, 0, stream>>>(x + (size_t)n * 786432, w_in, b_in, h1T);
            conv_mfma_k<256, 64, 128, true><<<256, 256, 0, stream>>>(
                h1T, wpack2, b_h1, nullptr, h2T + (size_t)n * 1048576);
        }
    }

    conv_mfma_k<64, 16, 256, false><<<128, 256, 0, stream>>>(
        h2T, wpack3, b_h2, h3, nullptr);

    conv4_k<<<512, 256, 0, stream>>>(h3, w_h3, b_h3, h4);
    resa_k<<<2048, 256, 0, stream>>>(h4, r0w1, t1);
    resb_k<<<512, 256, 0, stream>>>(h4, t1, r0w2, h5);
    resa_k<<<2048, 256, 0, stream>>>(h5, r1w1, t1);
    resb_k<<<512, 256, 0, stream>>>(h5, t1, r1w2, h6);

    embnorm_k<<<2, 256, 0, stream>>>(emb, en);
    vq_k<<<512, 256, 0, stream>>>(h6, emb, en, out, mse, hist);
    final_k<<<1, 512, 0, stream>>>(mse, hist, out);
}

// Round 8
// 1183.475 us; speedup vs baseline: 33.1043x; 1.4621x over previous
//
#include <hip/hip_runtime.h>
#include <hip/hip_bf16.h>

typedef __hip_bfloat16 bf16;
typedef __attribute__((ext_vector_type(4))) float f32x4;
typedef __attribute__((ext_vector_type(8))) short short8;

// ===========================================================================
// conv1 -> NHWC bf16: 4x4 s2 p1, Cin=3 Cout=128, 512->256.
// ===========================================================================
__global__ __launch_bounds__(256) void conv1n_k(const float* __restrict__ x,
        const float* __restrict__ w, const float* __restrict__ bias,
        bf16* __restrict__ h1T)
{
    int bid = blockIdx.x;
    int pxt = bid & 1023, img = bid >> 10;
    int oh0 = (pxt >> 5) * 8, ow0 = (pxt & 31) * 8;
    const float* xi = x + (size_t)img * 786432;
    bf16* oT = h1T + (size_t)img * 8388608;
    int t = threadIdx.x;
    int px = t >> 2, cog = t & 3;
    int py = px >> 3, qx = px & 7;

    __shared__ __align__(16) float pt1[3 * 18 * 18];
    __shared__ __align__(16) float wl[6144];

    for (int i = t; i < 6144; i += 256) {
        int u4b = i / 768; int r1 = i - u4b * 768;
        int tapidx = r1 >> 4; int r2 = r1 & 15;
        int cog2 = r2 >> 2, e = r2 & 3;
        int co = cog2 * 32 + u4b * 4 + e;
        wl[i] = w[co * 48 + tapidx];
    }
    int ihb = oh0 * 2 - 1, iwb = ow0 * 2 - 1;
    for (int i = t; i < 972; i += 256) {
        int ci = i / 324; int r1 = i - ci * 324;
        int r = r1 / 18, c = r1 - r * 18;
        int ih = ihb + r, iw = iwb + c;
        float v = 0.f;
        if ((unsigned)ih < 512u && (unsigned)iw < 512u)
            v = xi[ci * 262144 + ih * 512 + iw];
        pt1[i] = v;
    }
    __syncthreads();

    float acc[32];
    #pragma unroll
    for (int i = 0; i < 32; ++i) acc[i] = 0.f;

    #pragma unroll
    for (int ci = 0; ci < 3; ++ci)
        #pragma unroll
        for (int kh = 0; kh < 4; ++kh)
            #pragma unroll
            for (int kw = 0; kw < 4; ++kw) {
                float pv = pt1[ci * 324 + (2 * py + kh) * 18 + 2 * qx + kw];
                int tapidx = ci * 16 + kh * 4 + kw;
                #pragma unroll
                for (int u4 = 0; u4 < 8; ++u4) {
                    f32x4 wv = *(const f32x4*)&wl[((u4 * 48 + tapidx) * 4 + cog) * 4];
                    acc[u4 * 4 + 0] += pv * wv[0];
                    acc[u4 * 4 + 1] += pv * wv[1];
                    acc[u4 * 4 + 2] += pv * wv[2];
                    acc[u4 * 4 + 3] += pv * wv[3];
                }
            }

    int co0 = cog * 32;
    size_t base = ((size_t)(oh0 + py) * 256 + (ow0 + qx)) * 128 + co0;
    #pragma unroll
    for (int i = 0; i < 16; ++i) {
        __hip_bfloat162 pr;
        pr.x = __float2bfloat16(fmaxf(bias[co0 + 2 * i] + acc[2 * i], 0.f));
        pr.y = __float2bfloat16(fmaxf(bias[co0 + 2 * i + 1] + acc[2 * i + 1], 0.f));
        *(__hip_bfloat162*)(oT + base + 2 * i) = pr;
    }
}

// ===========================================================================
// weight pack: wpack[tap 0..49][ci>>3][co 0..255][ci&7] bf16 (tap49 unused).
// ===========================================================================
template <int CI>
__global__ void wpack_k(const float* __restrict__ w, bf16* __restrict__ wp)
{
    int i = blockIdx.x * 256 + threadIdx.x;
    int cil = i & 7; int co = (i >> 3) & 255; int r = i >> 11;
    int cib8 = r % (CI / 8); int tap = r / (CI / 8);
    float v = 0.f;
    if (tap < 49) v = w[co * (CI * 49) + (cib8 * 8 + cil) * 49 + tap];
    wp[i] = __float2bfloat16(v);
}

// ===========================================================================
// implicit-GEMM MFMA 7x7 s4 p2 conv, v2: all-256-co blocks, chunk=32ci,
// kstep = 1 tap (K=32). LDS patch layout pt2[ci_pair 0..15][pos'], row
// stride 1227 words, column-permuted pos' = r*35 + (c&3)*9 + (c>>2) so
// B-frag qx-lanes hit bank stride 1 (conflict-~free).
// BUGFIX r7->r8: compute-side index must use c = 4*qxl + kw BEFORE the
// (c&3)/(c>>2) split. The old 'kw*9 + qxl' form was only valid for kw<4;
// kw>=4 read +35 (one row) off and overran LDS on row 15 -> inf.
// conv2: IH=256 OH=64 CI=128 SPLIT=1, fused bias+relu -> NHWC bf16.
// conv3: IH=64 OH=16 CI=256 SPLIT=8 -> f32 atomic partials.
// ===========================================================================
template <int IH, int OH, int CI, int SPLIT, bool WRITE_T>
__global__ __launch_bounds__(256) void conv_mfma2_k(
        const bf16* __restrict__ inT, const bf16* __restrict__ wpack,
        const float* __restrict__ bias, float* __restrict__ outA,
        bf16* __restrict__ outT)
{
    constexpr int TPD = OH / 8;
    constexpr int NT = TPD * TPD;
    constexpr int CPB = (CI / 32) / SPLIT;     // chunks per block
    constexpr int CIB8 = CI / 8;
    constexpr int RS = 1227;

    int bid = blockIdx.x;
    int pxt = bid % NT;
    int rest = bid / NT;
    int img = rest & 7;
    int split = rest >> 3;
    int oh0 = (pxt / TPD) * 8, ow0 = (pxt % TPD) * 8;

    int t = threadIdx.x;
    int wave = t >> 6, lane = t & 63;
    int quad = lane >> 4, l15 = lane & 15;

    const bf16* inb = inT + (size_t)img * ((size_t)IH * IH * CI);

    __shared__ uint pt2[16 * RS];              // 78.5 KB

    f32x4 zero = {0.f, 0.f, 0.f, 0.f};
    f32x4 acc[4][4];
    #pragma unroll
    for (int a = 0; a < 4; ++a)
        #pragma unroll
        for (int b = 0; b < 4; ++b) acc[a][b] = zero;

    int ihb = oh0 * 4 - 2, iwb = ow0 * 4 - 2;
    int qxl = l15 & 7, pyl = l15 >> 3;

    for (int cc = 0; cc < CPB; ++cc) {
        int ch = split * CPB + cc;
        __syncthreads();
        for (int i = t; i < 4900; i += 256) {
            int pos = i >> 2, g = i & 3;
            int r = pos / 35, c = pos - r * 35;
            int ih = ihb + r, iw = iwb + c;
            uint4 v = make_uint4(0u, 0u, 0u, 0u);
            if ((unsigned)ih < (unsigned)IH && (unsigned)iw < (unsigned)IH)
                v = *(const uint4*)(inb + ((size_t)(ih * IH + iw) * CI + ch * 32 + g * 8));
            int posp = r * 35 + (c & 3) * 9 + (c >> 2);
            pt2[(4 * g + 0) * RS + posp] = v.x;
            pt2[(4 * g + 1) * RS + posp] = v.y;
            pt2[(4 * g + 2) * RS + posp] = v.z;
            pt2[(4 * g + 3) * RS + posp] = v.w;
        }
        __syncthreads();

        const bf16* abase = wpack + ((size_t)(ch * 4 + quad) * 256 + wave * 64 + l15) * 8;
        for (int tap = 0; tap < 49; ++tap) {
            int kh = tap / 7, kw = tap - kh * 7;
            short8 a[4];
            #pragma unroll
            for (int ct = 0; ct < 4; ++ct)
                a[ct] = *(const short8*)(abase + ((size_t)tap * CIB8 * 256 + ct * 16) * 8);
            int c = qxl * 4 + kw;                                  // BUGFIX
            int pbase = kh * 35 + (c & 3) * 9 + (c >> 2) + pyl * 140;
            #pragma unroll
            for (int pt = 0; pt < 4; ++pt) {
                int posp = pbase + pt * 280;
                union { short8 v; uint u[4]; } b;
                b.u[0] = pt2[(quad * 4 + 0) * RS + posp];
                b.u[1] = pt2[(quad * 4 + 1) * RS + posp];
                b.u[2] = pt2[(quad * 4 + 2) * RS + posp];
                b.u[3] = pt2[(quad * 4 + 3) * RS + posp];
                #pragma unroll
                for (int ct = 0; ct < 4; ++ct)
                    acc[ct][pt] = __builtin_amdgcn_mfma_f32_16x16x32_bf16(
                        a[ct], b.v, acc[ct][pt], 0, 0, 0);
            }
        }
    }

    #pragma unroll
    for (int ct = 0; ct < 4; ++ct) {
        int cobase = wave * 64 + ct * 16 + quad * 4;
        #pragma unroll
        for (int pt = 0; pt < 4; ++pt) {
            int px = pt * 16 + l15;
            int oh = oh0 + (px >> 3), ow = ow0 + (px & 7);
            #pragma unroll
            for (int r = 0; r < 4; ++r) {
                int co = cobase + r;
                float v = acc[ct][pt][r];
                if (WRITE_T) {
                    float o = fmaxf(bias[co] + v, 0.f);
                    outT[(size_t)img * (OH * OH * 256) + (size_t)(oh * OH + ow) * 256 + co]
                        = __float2bfloat16(o);
                } else {
                    atomicAdd(&outA[(size_t)img * (OH * OH * 256) + (size_t)co * (OH * OH)
                                    + oh * OH + ow], v);
                }
            }
        }
    }
}

// combine3: h3 = relu(bias + p3), 524288 elems, [img][co][16][16]
__global__ void combine3_k(const float* __restrict__ p3, const float* __restrict__ bias,
                           float* __restrict__ h3)
{
    int idx = blockIdx.x * 256 + threadIdx.x;
    int co = (idx >> 8) & 255;
    h3[idx] = fmaxf(bias[co] + p3[idx], 0.f);
}

// conv4: 3x3 s2 p1, 256->256, 16->8 (f32 NCHW). grid 512.
__global__ void conv4_k(const float* __restrict__ in, const float* __restrict__ w,
                        const float* __restrict__ bias, float* __restrict__ out)
{
    int idx = blockIdx.x * 256 + threadIdx.x;
    int ow = idx & 7;
    int oh = (idx >> 3) & 7;
    int co = (idx >> 6) & 255;
    int n  = idx >> 14;
    float acc = bias[co];
    const float* ib = in + (size_t)n * 65536;
    const float* wbase = w + (size_t)co * 2304;
    for (int ci = 0; ci < 256; ++ci) {
        const float* ip = ib + (size_t)ci * 256;
        const float* wp = wbase + ci * 9;
        #pragma unroll
        for (int kh = 0; kh < 3; ++kh) {
            int ih = oh * 2 - 1 + kh;
            if ((unsigned)ih < 16u) {
                #pragma unroll
                for (int kw = 0; kw < 3; ++kw) {
                    int iw = ow * 2 - 1 + kw;
                    if ((unsigned)iw < 16u)
                        acc += ip[ih * 16 + iw] * wp[kh * 3 + kw];
                }
            }
        }
    }
    out[idx] = fmaxf(acc, 0.f);
}

// residual a: t1 = conv1x3 over relu(h), 256->1024. grid 2048.
__global__ void resa_k(const float* __restrict__ h, const float* __restrict__ w,
                       float* __restrict__ t1)
{
    int idx = blockIdx.x * 256 + threadIdx.x;
    int x = idx & 7;
    int y = (idx >> 3) & 7;
    int co = (idx >> 6) & 1023;
    int n  = idx >> 16;
    float acc = 0.f;
    const float* hb = h + (size_t)n * 16384;
    const float* wbase = w + (size_t)co * 768;
    for (int ci = 0; ci < 256; ++ci) {
        const float* row = hb + (size_t)ci * 64 + y * 8;
        const float* wp = wbase + ci * 3;
        #pragma unroll
        for (int kx = 0; kx < 3; ++kx) {
            int xx = x - 1 + kx;
            if ((unsigned)xx < 8u)
                acc += fmaxf(row[xx], 0.f) * wp[kx];
        }
    }
    t1[idx] = acc;
}

// residual b: h_new = h_old + conv1x1 over relu(t1), 1024->256. grid 512.
__global__ void resb_k(const float* __restrict__ h_old, const float* __restrict__ t1,
                       const float* __restrict__ w, float* __restrict__ h_new)
{
    int idx = blockIdx.x * 256 + threadIdx.x;
    int x = idx & 7;
    int y = (idx >> 3) & 7;
    int co = (idx >> 6) & 255;
    int n  = idx >> 14;
    float acc = h_old[idx];
    const float* tb = t1 + (size_t)n * 65536 + y * 8 + x;
    const float* wp = w + (size_t)co * 1024;
    for (int ci = 0; ci < 1024; ++ci)
        acc += fmaxf(tb[(size_t)ci * 64], 0.f) * wp[ci];
    h_new[idx] = acc;
}

__global__ void embnorm_k(const float* __restrict__ emb, float* __restrict__ en)
{
    int k = blockIdx.x * 256 + threadIdx.x;
    const float* e = emb + (size_t)k * 256;
    float s = 0.f;
    for (int d = 0; d < 256; ++d) { float v = e[d]; s += v * v; }
    en[k] = s;
}

// VQ: one block per latent row (512 rows), D=256, K=512.
__global__ void vq_k(const float* __restrict__ h, const float* __restrict__ emb,
                     const float* __restrict__ en, float* __restrict__ out,
                     float* __restrict__ mse_acc, int* __restrict__ hist)
{
    int row = blockIdx.x;
    int b = row >> 6, y = (row >> 3) & 7, xx = row & 7;
    int t = threadIdx.x;
    __shared__ float lat[256];
    __shared__ float sdist[256];
    __shared__ int   sidx[256];

    float l = fmaxf(h[((size_t)(b * 256 + t) * 8 + y) * 8 + xx], 0.f);
    lat[t] = l;
    __syncthreads();

    float d0 = 0.f, d1 = 0.f;
    const float* e0 = emb + (size_t)t * 256;
    const float* e1 = emb + (size_t)(t + 256) * 256;
    for (int d = 0; d < 256; ++d) {
        float lv = lat[d];
        d0 += lv * e0[d];
        d1 += lv * e1[d];
    }
    d0 = en[t] - 2.f * d0;
    d1 = en[t + 256] - 2.f * d1;
    float best_d = d0; int best_i = t;
    if (d1 < best_d) { best_d = d1; best_i = t + 256; }
    sdist[t] = best_d; sidx[t] = best_i;
    __syncthreads();
    for (int s = 128; s > 0; s >>= 1) {
        if (t < s) {
            float od = sdist[t + s]; int oi = sidx[t + s];
            if (od < sdist[t] || (od == sdist[t] && oi < sidx[t])) {
                sdist[t] = od; sidx[t] = oi;
            }
        }
        __syncthreads();
    }
    int idx = sidx[0];

    float q = emb[(size_t)idx * 256 + t];
    out[((size_t)(b * 256 + t) * 8 + y) * 8 + xx] = q;
    float diff = q - lat[t];
    __syncthreads();
    sdist[t] = diff * diff;
    __syncthreads();
    for (int s = 128; s > 0; s >>= 1) {
        if (t < s) sdist[t] += sdist[t + s];
        __syncthreads();
    }
    if (t == 0) {
        atomicAdd(mse_acc, sdist[0]);
        atomicAdd(&hist[idx], 1);
    }
}

__global__ void final_k(const float* __restrict__ mse_acc, const int* __restrict__ hist,
                        float* __restrict__ out)
{
    __shared__ float sh[512];
    int t = threadIdx.x;
    float p = (float)hist[t] / 512.f;
    sh[t] = p * logf(p + 1e-10f);
    __syncthreads();
    for (int s = 256; s > 0; s >>= 1) {
        if (t < s) sh[t] += sh[t + s];
        __syncthreads();
    }
    if (t == 0) {
        float loss = 2.f * mse_acc[0] / (512.f * 256.f);
        float perp = expf(-sh[0]);
        out[131072] = loss;
        out[131073] = perp;
    }
}

// ===========================================================================
extern "C" void kernel_launch(void* const* d_in, const int* in_sizes, int n_in,
                              void* d_out, int out_size, void* d_ws, size_t ws_size,
                              hipStream_t stream)
{
    const float* x    = (const float*)d_in[0];
    const float* w_in = (const float*)d_in[1];
    const float* b_in = (const float*)d_in[2];
    const float* w_h1 = (const float*)d_in[3];
    const float* b_h1 = (const float*)d_in[4];
    const float* w_h2 = (const float*)d_in[5];
    const float* b_h2 = (const float*)d_in[6];
    const float* w_h3 = (const float*)d_in[7];
    const float* b_h3 = (const float*)d_in[8];
    const float* r0w1 = (const float*)d_in[9];
    const float* r0w2 = (const float*)d_in[10];
    const float* r1w1 = (const float*)d_in[11];
    const float* r1w2 = (const float*)d_in[12];
    const float* emb  = (const float*)d_in[13];
    float* out = (float*)d_out;

    char* ws = (char*)d_ws;
    size_t off = 0;
    auto alloc = [&](size_t bytes) -> void* {
        void* p = ws + off;
        off += (bytes + 255) & ~(size_t)255;
        return p;
    };

    float* h6  = (float*)alloc(131072ull * 4);
    float* en  = (float*)alloc(512 * 4);
    float* mse = (float*)alloc(256);
    int*  hist = (int*)alloc(512 * 4);
    float* p3  = (float*)alloc(524288ull * 4);     // conv3 partials
    float* h3  = (float*)alloc(524288ull * 4);     // [8,256,16,16] NCHW f32
    float* h4  = (float*)alloc(131072ull * 4);
    float* t1  = (float*)alloc(524288ull * 4);
    float* h5  = (float*)alloc(131072ull * 4);
    bf16* wpack2 = (bf16*)alloc(1638400ull * 2);   // 50*16*256*8
    bf16* wpack3 = (bf16*)alloc(3276800ull * 2);   // 50*32*256*8
    bf16* h2T  = (bf16*)alloc(8388608ull * 2);     // [8,64,64,256] NHWC bf16
    size_t base_end = off;

    const size_t H1TI = 8388608;                   // per-image h1T elems
    size_t needFull = base_end + H1TI * 8 * 2 + 4096;
    bool full = ws_size >= needFull;
    bf16* h1T = (bf16*)alloc(full ? H1TI * 8 * 2 : H1TI * 2);

    hipMemsetAsync(mse, 0, 4, stream);
    hipMemsetAsync(hist, 0, 512 * 4, stream);
    hipMemsetAsync(p3, 0, 524288ull * 4, stream);

    wpack_k<128><<<6400, 256, 0, stream>>>(w_h1, wpack2);
    wpack_k<256><<<12800, 256, 0, stream>>>(w_h2, wpack3);

    if (full) {
        conv1n_k<<<8192, 256, 0, stream>>>(x, w_in, b_in, h1T);
        conv_mfma2_k<256, 64, 128, 1, true><<<512, 256, 0, stream>>>(
            h1T, wpack2, b_h1, nullptr, h2T);
    } else {
        for (int n = 0; n < 8; ++n) {
            conv1n_k<<<1024, 256, 0, stream>>>(x + (size_t)n * 786432, w_in, b_in, h1T);
            conv_mfma2_k<256, 64, 128, 1, true><<<64, 256, 0, stream>>>(
                h1T, wpack2, b_h1, nullptr, h2T + (size_t)n * 1048576);
        }
    }

    conv_mfma2_k<64, 16, 256, 8, false><<<256, 256, 0, stream>>>(
        h2T, wpack3, b_h2, p3, nullptr);
    combine3_k<<<2048, 256, 0, stream>>>(p3, b_h2, h3);

    conv4_k<<<512, 256, 0, stream>>>(h3, w_h3, b_h3, h4);
    resa_k<<<2048, 256, 0, stream>>>(h4, r0w1, t1);
    resb_k<<<512, 256, 0, stream>>>(h4, t1, r0w2, h5);
    resa_k<<<2048, 256, 0, stream>>>(h5, r1w1, t1);
    resb_k<<<512, 256, 0, stream>>>(h5, t1, r1w2, h6);

    embnorm_k<<<2, 256, 0, stream>>>(emb, en);
    vq_k<<<512, 256, 0, stream>>>(h6, emb, en, out, mse, hist);
    final_k<<<1, 512, 0, stream>>>(mse, hist, out);
}

// Round 9
// 695.311 us; speedup vs baseline: 56.3461x; 1.7021x over previous
//
#include <hip/hip_runtime.h>
#include <hip/hip_bf16.h>

typedef __hip_bfloat16 bf16;
typedef __attribute__((ext_vector_type(4))) float f32x4;
typedef __attribute__((ext_vector_type(8))) short short8;

__device__ __forceinline__ float b2f(bf16 v) { return __bfloat162float(v); }
// relu on a packed pair of bf16 (zero any half with sign bit set)
__device__ __forceinline__ uint relu2(uint v)
{
    uint r = v;
    if (r & 0x8000u)     r &= 0xFFFF0000u;
    if (r & 0x80000000u) r &= 0x0000FFFFu;
    return r;
}

// ===========================================================================
// conv1 -> NHWC bf16: 4x4 s2 p1, Cin=3 Cout=128, 512->256.
// ===========================================================================
__global__ __launch_bounds__(256) void conv1n_k(const float* __restrict__ x,
        const float* __restrict__ w, const float* __restrict__ bias,
        bf16* __restrict__ h1T)
{
    int bid = blockIdx.x;
    int pxt = bid & 1023, img = bid >> 10;
    int oh0 = (pxt >> 5) * 8, ow0 = (pxt & 31) * 8;
    const float* xi = x + (size_t)img * 786432;
    bf16* oT = h1T + (size_t)img * 8388608;
    int t = threadIdx.x;
    int px = t >> 2, cog = t & 3;
    int py = px >> 3, qx = px & 7;

    __shared__ __align__(16) float pt1[3 * 18 * 18];
    __shared__ __align__(16) float wl[6144];

    for (int i = t; i < 6144; i += 256) {
        int u4b = i / 768; int r1 = i - u4b * 768;
        int tapidx = r1 >> 4; int r2 = r1 & 15;
        int cog2 = r2 >> 2, e = r2 & 3;
        int co = cog2 * 32 + u4b * 4 + e;
        wl[i] = w[co * 48 + tapidx];
    }
    int ihb = oh0 * 2 - 1, iwb = ow0 * 2 - 1;
    for (int i = t; i < 972; i += 256) {
        int ci = i / 324; int r1 = i - ci * 324;
        int r = r1 / 18, c = r1 - r * 18;
        int ih = ihb + r, iw = iwb + c;
        float v = 0.f;
        if ((unsigned)ih < 512u && (unsigned)iw < 512u)
            v = xi[ci * 262144 + ih * 512 + iw];
        pt1[i] = v;
    }
    __syncthreads();

    float acc[32];
    #pragma unroll
    for (int i = 0; i < 32; ++i) acc[i] = 0.f;

    #pragma unroll
    for (int ci = 0; ci < 3; ++ci)
        #pragma unroll
        for (int kh = 0; kh < 4; ++kh)
            #pragma unroll
            for (int kw = 0; kw < 4; ++kw) {
                float pv = pt1[ci * 324 + (2 * py + kh) * 18 + 2 * qx + kw];
                int tapidx = ci * 16 + kh * 4 + kw;
                #pragma unroll
                for (int u4 = 0; u4 < 8; ++u4) {
                    f32x4 wv = *(const f32x4*)&wl[((u4 * 48 + tapidx) * 4 + cog) * 4];
                    acc[u4 * 4 + 0] += pv * wv[0];
                    acc[u4 * 4 + 1] += pv * wv[1];
                    acc[u4 * 4 + 2] += pv * wv[2];
                    acc[u4 * 4 + 3] += pv * wv[3];
                }
            }

    int co0 = cog * 32;
    size_t base = ((size_t)(oh0 + py) * 256 + (ow0 + qx)) * 128 + co0;
    #pragma unroll
    for (int i = 0; i < 16; ++i) {
        __hip_bfloat162 pr;
        pr.x = __float2bfloat16(fmaxf(bias[co0 + 2 * i] + acc[2 * i], 0.f));
        pr.y = __float2bfloat16(fmaxf(bias[co0 + 2 * i + 1] + acc[2 * i + 1], 0.f));
        *(__hip_bfloat162*)(oT + base + 2 * i) = pr;
    }
}

// ===========================================================================
// weight pack (7x7 convs): wpack[tap 0..49][ci>>3][co 0..255][ci&7] bf16.
// ===========================================================================
template <int CI>
__global__ void wpack_k(const float* __restrict__ w, bf16* __restrict__ wp)
{
    int i = blockIdx.x * 256 + threadIdx.x;
    int cil = i & 7; int co = (i >> 3) & 255; int r = i >> 11;
    int cib8 = r % (CI / 8); int tap = r / (CI / 8);
    float v = 0.f;
    if (tap < 49) v = w[co * (CI * 49) + (cib8 * 8 + cil) * 49 + tap];
    wp[i] = __float2bfloat16(v);
}

// generic pack: OIHW f32 [CO][CIB8*8][KT] -> [tap][cib8][co][8] bf16
template <int KT, int CO, int CIB8>
__global__ void wpack_g(const float* __restrict__ w, bf16* __restrict__ wp)
{
    int i = blockIdx.x * 256 + threadIdx.x;     // KT*CIB8*CO*8 total
    int cil = i & 7; int co = (i >> 3) & (CO - 1);
    int r = (i >> 3) / CO;
    int cib8 = r % CIB8; int tap = r / CIB8;
    wp[i] = __float2bfloat16(w[(size_t)co * (CIB8 * 8 * KT) + (cib8 * 8 + cil) * KT + tap]);
}

// ===========================================================================
// implicit-GEMM MFMA 7x7 s4 p2 conv (conv2/conv3). Same as round 8 (passed).
// ===========================================================================
template <int IH, int OH, int CI, int SPLIT, bool WRITE_T>
__global__ __launch_bounds__(256) void conv_mfma2_k(
        const bf16* __restrict__ inT, const bf16* __restrict__ wpack,
        const float* __restrict__ bias, float* __restrict__ outA,
        bf16* __restrict__ outT)
{
    constexpr int TPD = OH / 8;
    constexpr int NT = TPD * TPD;
    constexpr int CPB = (CI / 32) / SPLIT;
    constexpr int CIB8 = CI / 8;
    constexpr int RS = 1227;

    int bid = blockIdx.x;
    int pxt = bid % NT;
    int rest = bid / NT;
    int img = rest & 7;
    int split = rest >> 3;
    int oh0 = (pxt / TPD) * 8, ow0 = (pxt % TPD) * 8;

    int t = threadIdx.x;
    int wave = t >> 6, lane = t & 63;
    int quad = lane >> 4, l15 = lane & 15;

    const bf16* inb = inT + (size_t)img * ((size_t)IH * IH * CI);

    __shared__ uint pt2[16 * RS];

    f32x4 zero = {0.f, 0.f, 0.f, 0.f};
    f32x4 acc[4][4];
    #pragma unroll
    for (int a = 0; a < 4; ++a)
        #pragma unroll
        for (int b = 0; b < 4; ++b) acc[a][b] = zero;

    int ihb = oh0 * 4 - 2, iwb = ow0 * 4 - 2;
    int qxl = l15 & 7, pyl = l15 >> 3;

    for (int cc = 0; cc < CPB; ++cc) {
        int ch = split * CPB + cc;
        __syncthreads();
        for (int i = t; i < 4900; i += 256) {
            int pos = i >> 2, g = i & 3;
            int r = pos / 35, c = pos - r * 35;
            int ih = ihb + r, iw = iwb + c;
            uint4 v = make_uint4(0u, 0u, 0u, 0u);
            if ((unsigned)ih < (unsigned)IH && (unsigned)iw < (unsigned)IH)
                v = *(const uint4*)(inb + ((size_t)(ih * IH + iw) * CI + ch * 32 + g * 8));
            int posp = r * 35 + (c & 3) * 9 + (c >> 2);
            pt2[(4 * g + 0) * RS + posp] = v.x;
            pt2[(4 * g + 1) * RS + posp] = v.y;
            pt2[(4 * g + 2) * RS + posp] = v.z;
            pt2[(4 * g + 3) * RS + posp] = v.w;
        }
        __syncthreads();

        const bf16* abase = wpack + ((size_t)(ch * 4 + quad) * 256 + wave * 64 + l15) * 8;
        for (int tap = 0; tap < 49; ++tap) {
            int kh = tap / 7, kw = tap - kh * 7;
            short8 a[4];
            #pragma unroll
            for (int ct = 0; ct < 4; ++ct)
                a[ct] = *(const short8*)(abase + ((size_t)tap * CIB8 * 256 + ct * 16) * 8);
            int c = qxl * 4 + kw;
            int pbase = kh * 35 + (c & 3) * 9 + (c >> 2) + pyl * 140;
            #pragma unroll
            for (int pt = 0; pt < 4; ++pt) {
                int posp = pbase + pt * 280;
                union { short8 v; uint u[4]; } b;
                b.u[0] = pt2[(quad * 4 + 0) * RS + posp];
                b.u[1] = pt2[(quad * 4 + 1) * RS + posp];
                b.u[2] = pt2[(quad * 4 + 2) * RS + posp];
                b.u[3] = pt2[(quad * 4 + 3) * RS + posp];
                #pragma unroll
                for (int ct = 0; ct < 4; ++ct)
                    acc[ct][pt] = __builtin_amdgcn_mfma_f32_16x16x32_bf16(
                        a[ct], b.v, acc[ct][pt], 0, 0, 0);
            }
        }
    }

    #pragma unroll
    for (int ct = 0; ct < 4; ++ct) {
        int cobase = wave * 64 + ct * 16 + quad * 4;
        #pragma unroll
        for (int pt = 0; pt < 4; ++pt) {
            int px = pt * 16 + l15;
            int oh = oh0 + (px >> 3), ow = ow0 + (px & 7);
            #pragma unroll
            for (int r = 0; r < 4; ++r) {
                int co = cobase + r;
                float v = acc[ct][pt][r];
                if (WRITE_T) {
                    float o = fmaxf(bias[co] + v, 0.f);
                    outT[(size_t)img * (OH * OH * 256) + (size_t)(oh * OH + ow) * 256 + co]
                        = __float2bfloat16(o);
                } else {
                    atomicAdd(&outA[(size_t)img * (OH * OH * 256) + (size_t)co * (OH * OH)
                                    + oh * OH + ow], v);
                }
            }
        }
    }
}

// combine3 -> NHWC bf16: h3T[(img*256+px)*256+co] = relu(bias+p3)
__global__ void combine3_k(const float* __restrict__ p3, const float* __restrict__ bias,
                           bf16* __restrict__ h3T)
{
    int idx = blockIdx.x * 256 + threadIdx.x;      // 524288
    int px = idx & 255;
    int co = (idx >> 8) & 255;
    int img = idx >> 16;
    float v = fmaxf(bias[co] + p3[idx], 0.f);
    h3T[((size_t)img * 256 + px) * 256 + co] = __float2bfloat16(v);
}

// ===========================================================================
// conv4 MFMA: 3x3 s2 p1, 256->256 ch, 16->8, NHWC bf16 in/out, relu.
// grid 8 (img). M=256co,N=64px,K=2304 ([tap 0..8][256 ci]).
// LDS: per-32ci chunk, 18x18 zero-padded patch, rows [ci_pair][325].
// ===========================================================================
__global__ __launch_bounds__(256) void conv4m_k(const bf16* __restrict__ h3T,
        const bf16* __restrict__ wp4, const float* __restrict__ bias,
        bf16* __restrict__ h4T)
{
    int img = blockIdx.x;
    int t = threadIdx.x;
    int wave = t >> 6, lane = t & 63;
    int quad = lane >> 4, l15 = lane & 15;

    __shared__ uint pt[16 * 325];                  // 20.8 KB

    for (int i = t; i < 16 * 325; i += 256) pt[i] = 0;

    f32x4 zero = {0.f, 0.f, 0.f, 0.f};
    f32x4 acc[4][4];
    #pragma unroll
    for (int a = 0; a < 4; ++a)
        #pragma unroll
        for (int b = 0; b < 4; ++b) acc[a][b] = zero;

    const bf16* inb = h3T + (size_t)img * 65536;

    for (int ch = 0; ch < 8; ++ch) {
        __syncthreads();
        for (int e = t; e < 4096; e += 256) {
            int cp = e & 15, px = e >> 4;
            int py = px >> 4, qx = px & 15;
            uint v = *(const uint*)(inb + (size_t)px * 256 + ch * 32 + cp * 2);
            pt[cp * 325 + (py + 1) * 18 + qx + 1] = v;
        }
        __syncthreads();

        for (int tap = 0; tap < 9; ++tap) {
            int kh = tap / 3, kw = tap - kh * 3;
            const bf16* abase = wp4 + ((size_t)((tap * 32 + ch * 4 + quad) * 256)
                                       + wave * 64 + l15) * 8;
            short8 a[4];
            #pragma unroll
            for (int ct = 0; ct < 4; ++ct)
                a[ct] = *(const short8*)(abase + ct * 16 * 8);
            #pragma unroll
            for (int pq = 0; pq < 4; ++pq) {
                int pyo = 2 * pq + (l15 >> 3);
                int ipos = (2 * pyo + kh) * 18 + 2 * (l15 & 7) + kw;
                union { short8 v; uint u[4]; } b;
                b.u[0] = pt[(quad * 4 + 0) * 325 + ipos];
                b.u[1] = pt[(quad * 4 + 1) * 325 + ipos];
                b.u[2] = pt[(quad * 4 + 2) * 325 + ipos];
                b.u[3] = pt[(quad * 4 + 3) * 325 + ipos];
                #pragma unroll
                for (int ct = 0; ct < 4; ++ct)
                    acc[ct][pq] = __builtin_amdgcn_mfma_f32_16x16x32_bf16(
                        a[ct], b.v, acc[ct][pq], 0, 0, 0);
            }
        }
    }

    #pragma unroll
    for (int ct = 0; ct < 4; ++ct) {
        int cobase = wave * 64 + ct * 16 + quad * 4;
        #pragma unroll
        for (int pq = 0; pq < 4; ++pq) {
            int px = pq * 16 + l15;
            #pragma unroll
            for (int r = 0; r < 4; ++r) {
                int co = cobase + r;
                float v = fmaxf(bias[co] + acc[ct][pq][r], 0.f);
                h4T[((size_t)img * 64 + px) * 256 + co] = __float2bfloat16(v);
            }
        }
    }
}

// ===========================================================================
// res-a MFMA: t1 = conv1x3(relu(h)), 256->1024, 8x8. NHWC bf16.
// grid 32 = 8 img x 4 co-groups. M=256(of 1024),N=64,K=768 ([dx 0..2][256ci]).
// LDS: whole image x-padded to 10, rows [ci_pair 0..127][81].
// ===========================================================================
__global__ __launch_bounds__(256) void resam_k(const bf16* __restrict__ hT,
        const bf16* __restrict__ wpA, bf16* __restrict__ t1T)
{
    int bid = blockIdx.x;
    int img = bid >> 2, g = bid & 3;
    int t = threadIdx.x;
    int wave = t >> 6, lane = t & 63;
    int quad = lane >> 4, l15 = lane & 15;

    __shared__ uint ph[128 * 81];                  // 41.5 KB

    for (int i = t; i < 128 * 81; i += 256) ph[i] = 0;
    __syncthreads();
    const bf16* inb = hT + (size_t)img * 16384;
    for (int e = t; e < 8192; e += 256) {
        int cp = e & 127, px = e >> 7;
        uint v = relu2(*(const uint*)(inb + (size_t)px * 256 + cp * 2));
        ph[cp * 81 + (px >> 3) * 10 + (px & 7) + 1] = v;
    }
    __syncthreads();

    f32x4 zero = {0.f, 0.f, 0.f, 0.f};
    f32x4 acc[4][4];
    #pragma unroll
    for (int a = 0; a < 4; ++a)
        #pragma unroll
        for (int b = 0; b < 4; ++b) acc[a][b] = zero;

    for (int ch = 0; ch < 8; ++ch) {
        for (int tap = 0; tap < 3; ++tap) {
            const bf16* abase = wpA + ((size_t)(tap * 32 + ch * 4 + quad) * 1024
                                       + g * 256 + wave * 64 + l15) * 8;
            short8 a[4];
            #pragma unroll
            for (int ct = 0; ct < 4; ++ct)
                a[ct] = *(const short8*)(abase + ct * 16 * 8);
            #pragma unroll
            for (int pq = 0; pq < 4; ++pq) {
                int py = 2 * pq + (l15 >> 3);
                int pos = py * 10 + (l15 & 7) + tap;
                union { short8 v; uint u[4]; } b;
                b.u[0] = ph[(ch * 16 + quad * 4 + 0) * 81 + pos];
                b.u[1] = ph[(ch * 16 + quad * 4 + 1) * 81 + pos];
                b.u[2] = ph[(ch * 16 + quad * 4 + 2) * 81 + pos];
                b.u[3] = ph[(ch * 16 + quad * 4 + 3) * 81 + pos];
                #pragma unroll
                for (int ct = 0; ct < 4; ++ct)
                    acc[ct][pq] = __builtin_amdgcn_mfma_f32_16x16x32_bf16(
                        a[ct], b.v, acc[ct][pq], 0, 0, 0);
            }
        }
    }

    #pragma unroll
    for (int ct = 0; ct < 4; ++ct) {
        int cobase = g * 256 + wave * 64 + ct * 16 + quad * 4;
        #pragma unroll
        for (int pq = 0; pq < 4; ++pq) {
            int px = pq * 16 + l15;
            #pragma unroll
            for (int r = 0; r < 4; ++r)
                t1T[((size_t)img * 64 + px) * 1024 + cobase + r]
                    = __float2bfloat16(acc[ct][pq][r]);
        }
    }
}

// ===========================================================================
// res-b MFMA: h_new = h_old + conv1x1(relu(t1)), 1024->256, 8x8. NHWC bf16.
// grid 8 (img). M=256,N=64,K=1024; 2 LDS stages of 16 chunks.
// ===========================================================================
__global__ __launch_bounds__(256) void resbm_k(const bf16* __restrict__ holdT,
        const bf16* __restrict__ t1T, const bf16* __restrict__ wpB,
        bf16* __restrict__ hnewT)
{
    int img = blockIdx.x;
    int t = threadIdx.x;
    int wave = t >> 6, lane = t & 63;
    int quad = lane >> 4, l15 = lane & 15;

    __shared__ uint pb[256 * 65];                  // 66.6 KB

    f32x4 zero = {0.f, 0.f, 0.f, 0.f};
    f32x4 acc[4][4];
    #pragma unroll
    for (int a = 0; a < 4; ++a)
        #pragma unroll
        for (int b = 0; b < 4; ++b) acc[a][b] = zero;

    const bf16* inb = t1T + (size_t)img * 65536;

    for (int s = 0; s < 2; ++s) {
        __syncthreads();
        for (int e = t; e < 16384; e += 256) {
            int cp = e & 255, px = e >> 8;
            uint v = relu2(*(const uint*)(inb + (size_t)px * 1024 + s * 512 + cp * 2));
            pb[cp * 65 + px] = v;
        }
        __syncthreads();

        for (int chl = 0; chl < 16; ++chl) {
            int ch = s * 16 + chl;
            const bf16* abase = wpB + ((size_t)(ch * 4 + quad) * 256
                                       + wave * 64 + l15) * 8;
            short8 a[4];
            #pragma unroll
            for (int ct = 0; ct < 4; ++ct)
                a[ct] = *(const short8*)(abase + ct * 16 * 8);
            #pragma unroll
            for (int pq = 0; pq < 4; ++pq) {
                int px = pq * 16 + l15;
                union { short8 v; uint u[4]; } b;
                b.u[0] = pb[(chl * 16 + quad * 4 + 0) * 65 + px];
                b.u[1] = pb[(chl * 16 + quad * 4 + 1) * 65 + px];
                b.u[2] = pb[(chl * 16 + quad * 4 + 2) * 65 + px];
                b.u[3] = pb[(chl * 16 + quad * 4 + 3) * 65 + px];
                #pragma unroll
                for (int ct = 0; ct < 4; ++ct)
                    acc[ct][pq] = __builtin_amdgcn_mfma_f32_16x16x32_bf16(
                        a[ct], b.v, acc[ct][pq], 0, 0, 0);
            }
        }
    }

    #pragma unroll
    for (int ct = 0; ct < 4; ++ct) {
        int cobase = wave * 64 + ct * 16 + quad * 4;
        #pragma unroll
        for (int pq = 0; pq < 4; ++pq) {
            int px = pq * 16 + l15;
            #pragma unroll
            for (int r = 0; r < 4; ++r) {
                int co = cobase + r;
                size_t o = ((size_t)img * 64 + px) * 256 + co;
                float v = b2f(holdT[o]) + acc[ct][pq][r];
                hnewT[o] = __float2bfloat16(v);
            }
        }
    }
}

__global__ void embnorm_k(const float* __restrict__ emb, float* __restrict__ en)
{
    int k = blockIdx.x * 256 + threadIdx.x;
    const float* e = emb + (size_t)k * 256;
    float s = 0.f;
    for (int d = 0; d < 256; ++d) { float v = e[d]; s += v * v; }
    en[k] = s;
}

// VQ: one block per latent row (512). Reads h6T NHWC bf16 (relu'd here).
__global__ void vq_k(const bf16* __restrict__ h6T, const float* __restrict__ emb,
                     const float* __restrict__ en, float* __restrict__ out,
                     float* __restrict__ mse_acc, int* __restrict__ hist)
{
    int row = blockIdx.x;
    int b = row >> 6, y = (row >> 3) & 7, xx = row & 7;
    int t = threadIdx.x;
    __shared__ float lat[256];
    __shared__ float sdist[256];
    __shared__ int   sidx[256];

    float l = fmaxf(b2f(h6T[(size_t)row * 256 + t]), 0.f);
    lat[t] = l;
    __syncthreads();

    float d0 = 0.f, d1 = 0.f;
    const float* e0 = emb + (size_t)t * 256;
    const float* e1 = emb + (size_t)(t + 256) * 256;
    for (int d = 0; d < 256; ++d) {
        float lv = lat[d];
        d0 += lv * e0[d];
        d1 += lv * e1[d];
    }
    d0 = en[t] - 2.f * d0;
    d1 = en[t + 256] - 2.f * d1;
    float best_d = d0; int best_i = t;
    if (d1 < best_d) { best_d = d1; best_i = t + 256; }
    sdist[t] = best_d; sidx[t] = best_i;
    __syncthreads();
    for (int s = 128; s > 0; s >>= 1) {
        if (t < s) {
            float od = sdist[t + s]; int oi = sidx[t + s];
            if (od < sdist[t] || (od == sdist[t] && oi < sidx[t])) {
                sdist[t] = od; sidx[t] = oi;
            }
        }
        __syncthreads();
    }
    int idx = sidx[0];

    float q = emb[(size_t)idx * 256 + t];
    out[((size_t)(b * 256 + t) * 8 + y) * 8 + xx] = q;
    float diff = q - lat[t];
    __syncthreads();
    sdist[t] = diff * diff;
    __syncthreads();
    for (int s = 128; s > 0; s >>= 1) {
        if (t < s) sdist[t] += sdist[t + s];
        __syncthreads();
    }
    if (t == 0) {
        atomicAdd(mse_acc, sdist[0]);
        atomicAdd(&hist[idx], 1);
    }
}

__global__ void final_k(const float* __restrict__ mse_acc, const int* __restrict__ hist,
                        float* __restrict__ out)
{
    __shared__ float sh[512];
    int t = threadIdx.x;
    float p = (float)hist[t] / 512.f;
    sh[t] = p * logf(p + 1e-10f);
    __syncthreads();
    for (int s = 256; s > 0; s >>= 1) {
        if (t < s) sh[t] += sh[t + s];
        __syncthreads();
    }
    if (t == 0) {
        float loss = 2.f * mse_acc[0] / (512.f * 256.f);
        float perp = expf(-sh[0]);
        out[131072] = loss;
        out[131073] = perp;
    }
}

// ===========================================================================
extern "C" void kernel_launch(void* const* d_in, const int* in_sizes, int n_in,
                              void* d_out, int out_size, void* d_ws, size_t ws_size,
                              hipStream_t stream)
{
    const float* x    = (const float*)d_in[0];
    const float* w_in = (const float*)d_in[1];
    const float* b_in = (const float*)d_in[2];
    const float* w_h1 = (const float*)d_in[3];
    const float* b_h1 = (const float*)d_in[4];
    const float* w_h2 = (const float*)d_in[5];
    const float* b_h2 = (const float*)d_in[6];
    const float* w_h3 = (const float*)d_in[7];
    const float* b_h3 = (const float*)d_in[8];
    const float* r0w1 = (const float*)d_in[9];
    const float* r0w2 = (const float*)d_in[10];
    const float* r1w1 = (const float*)d_in[11];
    const float* r1w2 = (const float*)d_in[12];
    const float* emb  = (const float*)d_in[13];
    float* out = (float*)d_out;

    char* ws = (char*)d_ws;
    size_t off = 0;
    auto alloc = [&](size_t bytes) -> void* {
        void* p = ws + off;
        off += (bytes + 255) & ~(size_t)255;
        return p;
    };

    float* en  = (float*)alloc(512 * 4);
    float* mse = (float*)alloc(256);
    int*  hist = (int*)alloc(512 * 4);
    float* p3  = (float*)alloc(524288ull * 4);     // conv3 partials
    bf16* h3T  = (bf16*)alloc(524288ull * 2);      // [8,256px,256c]
    bf16* h4T  = (bf16*)alloc(131072ull * 2);      // [8,64px,256c]
    bf16* t1T  = (bf16*)alloc(524288ull * 2);      // [8,64px,1024c]
    bf16* h5T  = (bf16*)alloc(131072ull * 2);
    bf16* h6T  = (bf16*)alloc(131072ull * 2);
    bf16* wpack2 = (bf16*)alloc(1638400ull * 2);   // conv2 50*16*256*8
    bf16* wpack3 = (bf16*)alloc(3276800ull * 2);   // conv3 50*32*256*8
    bf16* wp4  = (bf16*)alloc(589824ull * 2);      // conv4 9*32*256*8
    bf16* wpA0 = (bf16*)alloc(786432ull * 2);      // resa 3*32*1024*8
    bf16* wpA1 = (bf16*)alloc(786432ull * 2);
    bf16* wpB0 = (bf16*)alloc(262144ull * 2);      // resb 128*256*8
    bf16* wpB1 = (bf16*)alloc(262144ull * 2);
    bf16* h2T  = (bf16*)alloc(8388608ull * 2);     // [8,64,64,256]
    size_t base_end = off;

    const size_t H1TI = 8388608;
    size_t needFull = base_end + H1TI * 8 * 2 + 4096;
    bool full = ws_size >= needFull;
    bf16* h1T = (bf16*)alloc(full ? H1TI * 8 * 2 : H1TI * 2);

    hipMemsetAsync(mse, 0, 4, stream);
    hipMemsetAsync(hist, 0, 512 * 4, stream);
    hipMemsetAsync(p3, 0, 524288ull * 4, stream);

    wpack_k<128><<<6400, 256, 0, stream>>>(w_h1, wpack2);
    wpack_k<256><<<12800, 256, 0, stream>>>(w_h2, wpack3);
    wpack_g<9, 256, 32><<<2304, 256, 0, stream>>>(w_h3, wp4);
    wpack_g<3, 1024, 32><<<3072, 256, 0, stream>>>(r0w1, wpA0);
    wpack_g<3, 1024, 32><<<3072, 256, 0, stream>>>(r1w1, wpA1);
    wpack_g<1, 256, 128><<<1024, 256, 0, stream>>>(r0w2, wpB0);
    wpack_g<1, 256, 128><<<1024, 256, 0, stream>>>(r1w2, wpB1);

    if (full) {
        conv1n_k<<<8192, 256, 0, stream>>>(x, w_in, b_in, h1T);
        conv_mfma2_k<256, 64, 128, 1, true><<<512, 256, 0, stream>>>(
            h1T, wpack2, b_h1, nullptr, h2T);
    } else {
        for (int n = 0; n < 8; ++n) {
            conv1n_k<<<1024, 256, 0, stream>>>(x + (size_t)n * 786432, w_in, b_in, h1T);
            conv_mfma2_k<256, 64, 128, 1, true><<<64, 256, 0, stream>>>(
                h1T, wpack2, b_h1, nullptr, h2T + (size_t)n * 1048576);
        }
    }

    conv_mfma2_k<64, 16, 256, 8, false><<<256, 256, 0, stream>>>(
        h2T, wpack3, b_h2, p3, nullptr);
    combine3_k<<<2048, 256, 0, stream>>>(p3, b_h2, h3T);

    conv4m_k<<<8, 256, 0, stream>>>(h3T, wp4, b_h3, h4T);
    resam_k<<<32, 256, 0, stream>>>(h4T, wpA0, t1T);
    resbm_k<<<8, 256, 0, stream>>>(h4T, t1T, wpB0, h5T);
    resam_k<<<32, 256, 0, stream>>>(h5T, wpA1, t1T);
    resbm_k<<<8, 256, 0, stream>>>(h5T, t1T, wpB1, h6T);

    embnorm_k<<<2, 256, 0, stream>>>(emb, en);
    vq_k<<<512, 256, 0, stream>>>(h6T, emb, en, out, mse, hist);
    final_k<<<1, 512, 0, stream>>>(mse, hist, out);
}

// Round 10
// 615.542 us; speedup vs baseline: 63.6481x; 1.1296x over previous
//
#include <hip/hip_runtime.h>
#include <hip/hip_bf16.h>

typedef __hip_bfloat16 bf16;
typedef __attribute__((ext_vector_type(4))) float f32x4;
typedef __attribute__((ext_vector_type(8))) short short8;

__device__ __forceinline__ float b2f(bf16 v) { return __bfloat162float(v); }
__device__ __forceinline__ ushort f2bu(float v)
{
    bf16 b = __float2bfloat16(v);
    return *(ushort*)&b;
}
// relu on a packed pair of bf16 (zero any half with sign bit set)
__device__ __forceinline__ uint relu2(uint v)
{
    uint r = v;
    if (r & 0x8000u)     r &= 0xFFFF0000u;
    if (r & 0x80000000u) r &= 0x0000FFFFu;
    return r;
}
__device__ __forceinline__ uint packbf2(float a, float b)
{
    uint lo = f2bu(a), hi = f2bu(b);
    return lo | (hi << 16);
}

// ===========================================================================
// conv1 weight pack: wp1[kb 0..7][co 0..127][j 0..7], k = kb*8+j is the
// OIHW inner index (ci*16+kh*4+kw); k>=48 zero (K pad 48->64). grid 32.
// ===========================================================================
__global__ void wpack1_k(const float* __restrict__ w, bf16* __restrict__ wp)
{
    int i = blockIdx.x * 256 + threadIdx.x;        // 8192
    int j = i & 7; int co = (i >> 3) & 127; int kb = i >> 10;
    int k = kb * 8 + j;
    float v = (k < 48) ? w[co * 48 + k] : 0.f;
    wp[i] = __float2bfloat16(v);
}

// ===========================================================================
// conv1 MFMA: 4x4 s2 p1, Cin=3 Cout=128, 512->256, NHWC bf16 out.
// GEMM M=128co, N=128px (8oh x 16ow), K=64 (48 real + 16 pad via zeroed
// ci=3 LDS plane). Wave: all 128 co (8 m-tiles) x 32 px (2 oh rows).
// B-frag: k = ks*32 + quad*8 + j -> ci = ks*2+(quad>>1) fixed per frag,
// kh0 = (quad&1)*2; j = (kh-kh0)*4 + kw -> 4 aligned ds_read_b32
// (iwl = 2*l15 even). Epilogue routed through LDS (row stride 136 u16 =
// 272 B, 16B-multiple) -> fully coalesced 256 B/px global writes.
// grid: 512 pxtiles * 8 img = 4096.
// ===========================================================================
__global__ __launch_bounds__(256) void conv1m_k(const float* __restrict__ x,
        const bf16* __restrict__ wp1, const float* __restrict__ bias,
        bf16* __restrict__ h1T)
{
    int bid = blockIdx.x;
    int pxt = bid & 511, img = bid >> 9;
    int tr = pxt >> 4, tc = pxt & 15;
    int oh0 = tr * 8, ow0 = tc * 16;
    const float* xi = x + (size_t)img * 786432;
    bf16* oT = h1T + (size_t)img * 8388608;

    int t = threadIdx.x;
    int wave = t >> 6, lane = t & 63;
    int quad = lane >> 4, l15 = lane & 15;

    __shared__ ushort xs[4 * 640];                 // [ci][ihl*35+iwl]; ci3 = 0
    __shared__ ushort ot[128 * 136];               // 34.8 KB epilogue staging

    int ihb = oh0 * 2 - 1, iwb = ow0 * 2 - 1;
    for (int i = t; i < 1836; i += 256) {
        int ci = i / 612; int r1 = i - ci * 612;
        int ihl = r1 / 34, iwl = r1 - ihl * 34;
        int ih = ihb + ihl, iw = iwb + iwl;
        float v = 0.f;
        if ((unsigned)ih < 512u && (unsigned)iw < 512u)
            v = xi[ci * 262144 + ih * 512 + iw];
        xs[ci * 640 + ihl * 35 + iwl] = f2bu(v);
    }
    for (int i = t; i < 640; i += 256) xs[3 * 640 + i] = 0;
    __syncthreads();

    f32x4 zero = {0.f, 0.f, 0.f, 0.f};
    f32x4 acc[8][2];
    #pragma unroll
    for (int m = 0; m < 8; ++m) { acc[m][0] = zero; acc[m][1] = zero; }

    int ci_b = quad >> 1;                          // + ks*2
    int kh0 = (quad & 1) * 2;
    int iwl0 = 2 * l15;

    #pragma unroll
    for (int ks = 0; ks < 2; ++ks) {
        union { short8 v; uint u[4]; } b[2];
        #pragma unroll
        for (int nt = 0; nt < 2; ++nt) {
            int py = wave * 2 + nt;
            int base = (ks * 2 + ci_b) * 640 + (2 * py + kh0) * 35 + iwl0;
            b[nt].u[0] = *(const uint*)&xs[base];
            b[nt].u[1] = *(const uint*)&xs[base + 2];
            b[nt].u[2] = *(const uint*)&xs[base + 35];
            b[nt].u[3] = *(const uint*)&xs[base + 37];
        }
        const bf16* abase = wp1 + ((size_t)(ks * 4 + quad) * 128 + l15) * 8;
        #pragma unroll
        for (int m = 0; m < 8; ++m) {
            short8 a = *(const short8*)(abase + m * 16 * 8);
            acc[m][0] = __builtin_amdgcn_mfma_f32_16x16x32_bf16(a, b[0].v, acc[m][0], 0, 0, 0);
            acc[m][1] = __builtin_amdgcn_mfma_f32_16x16x32_bf16(a, b[1].v, acc[m][1], 0, 0, 0);
        }
    }

    // epilogue: bias+relu -> ot[pxl][co] -> coalesced global writes
    #pragma unroll
    for (int m = 0; m < 8; ++m) {
        int cobase = m * 16 + quad * 4;
        float b0 = bias[cobase], b1 = bias[cobase + 1];
        float b2 = bias[cobase + 2], b3 = bias[cobase + 3];
        #pragma unroll
        for (int nt = 0; nt < 2; ++nt) {
            int pxl = (wave * 2 + nt) * 16 + l15;
            uint w0 = packbf2(fmaxf(b0 + acc[m][nt][0], 0.f),
                              fmaxf(b1 + acc[m][nt][1], 0.f));
            uint w1 = packbf2(fmaxf(b2 + acc[m][nt][2], 0.f),
                              fmaxf(b3 + acc[m][nt][3], 0.f));
            *(uint*)&ot[pxl * 136 + cobase]     = w0;
            *(uint*)&ot[pxl * 136 + cobase + 2] = w1;
        }
    }
    __syncthreads();
    {
        int pxl = t >> 1, half = t & 1;
        int oh = oh0 + (pxl >> 4), ow = ow0 + (pxl & 15);
        const uint4* src = (const uint4*)&ot[pxl * 136 + half * 64];
        uint4* dst = (uint4*)(oT + ((size_t)(oh * 256 + ow)) * 128 + half * 64);
        #pragma unroll
        for (int i = 0; i < 8; ++i) dst[i] = src[i];
    }
}

// ===========================================================================
// weight pack (7x7 convs): wpack[tap 0..49][ci>>3][co 0..255][ci&7] bf16.
// ===========================================================================
template <int CI>
__global__ void wpack_k(const float* __restrict__ w, bf16* __restrict__ wp)
{
    int i = blockIdx.x * 256 + threadIdx.x;
    int cil = i & 7; int co = (i >> 3) & 255; int r = i >> 11;
    int cib8 = r % (CI / 8); int tap = r / (CI / 8);
    float v = 0.f;
    if (tap < 49) v = w[co * (CI * 49) + (cib8 * 8 + cil) * 49 + tap];
    wp[i] = __float2bfloat16(v);
}

// generic pack: OIHW f32 [CO][CIB8*8][KT] -> [tap][cib8][co][8] bf16
template <int KT, int CO, int CIB8>
__global__ void wpack_g(const float* __restrict__ w, bf16* __restrict__ wp)
{
    int i = blockIdx.x * 256 + threadIdx.x;
    int cil = i & 7; int co = (i >> 3) & (CO - 1);
    int r = (i >> 3) / CO;
    int cib8 = r % CIB8; int tap = r / CIB8;
    wp[i] = __float2bfloat16(w[(size_t)co * (CIB8 * 8 * KT) + (cib8 * 8 + cil) * KT + tap]);
}

// ===========================================================================
// implicit-GEMM MFMA 7x7 s4 p2 conv (conv2/conv3). Unchanged (passed R8/R9).
// ===========================================================================
template <int IH, int OH, int CI, int SPLIT, bool WRITE_T>
__global__ __launch_bounds__(256) void conv_mfma2_k(
        const bf16* __restrict__ inT, const bf16* __restrict__ wpack,
        const float* __restrict__ bias, float* __restrict__ outA,
        bf16* __restrict__ outT)
{
    constexpr int TPD = OH / 8;
    constexpr int NT = TPD * TPD;
    constexpr int CPB = (CI / 32) / SPLIT;
    constexpr int CIB8 = CI / 8;
    constexpr int RS = 1227;

    int bid = blockIdx.x;
    int pxt = bid % NT;
    int rest = bid / NT;
    int img = rest & 7;
    int split = rest >> 3;
    int oh0 = (pxt / TPD) * 8, ow0 = (pxt % TPD) * 8;

    int t = threadIdx.x;
    int wave = t >> 6, lane = t & 63;
    int quad = lane >> 4, l15 = lane & 15;

    const bf16* inb = inT + (size_t)img * ((size_t)IH * IH * CI);

    __shared__ uint pt2[16 * RS];

    f32x4 zero = {0.f, 0.f, 0.f, 0.f};
    f32x4 acc[4][4];
    #pragma unroll
    for (int a = 0; a < 4; ++a)
        #pragma unroll
        for (int b = 0; b < 4; ++b) acc[a][b] = zero;

    int ihb = oh0 * 4 - 2, iwb = ow0 * 4 - 2;
    int qxl = l15 & 7, pyl = l15 >> 3;

    for (int cc = 0; cc < CPB; ++cc) {
        int ch = split * CPB + cc;
        __syncthreads();
        for (int i = t; i < 4900; i += 256) {
            int pos = i >> 2, g = i & 3;
            int r = pos / 35, c = pos - r * 35;
            int ih = ihb + r, iw = iwb + c;
            uint4 v = make_uint4(0u, 0u, 0u, 0u);
            if ((unsigned)ih < (unsigned)IH && (unsigned)iw < (unsigned)IH)
                v = *(const uint4*)(inb + ((size_t)(ih * IH + iw) * CI + ch * 32 + g * 8));
            int posp = r * 35 + (c & 3) * 9 + (c >> 2);
            pt2[(4 * g + 0) * RS + posp] = v.x;
            pt2[(4 * g + 1) * RS + posp] = v.y;
            pt2[(4 * g + 2) * RS + posp] = v.z;
            pt2[(4 * g + 3) * RS + posp] = v.w;
        }
        __syncthreads();

        const bf16* abase = wpack + ((size_t)(ch * 4 + quad) * 256 + wave * 64 + l15) * 8;
        for (int tap = 0; tap < 49; ++tap) {
            int kh = tap / 7, kw = tap - kh * 7;
            short8 a[4];
            #pragma unroll
            for (int ct = 0; ct < 4; ++ct)
                a[ct] = *(const short8*)(abase + ((size_t)tap * CIB8 * 256 + ct * 16) * 8);
            int c = qxl * 4 + kw;
            int pbase = kh * 35 + (c & 3) * 9 + (c >> 2) + pyl * 140;
            #pragma unroll
            for (int pt = 0; pt < 4; ++pt) {
                int posp = pbase + pt * 280;
                union { short8 v; uint u[4]; } b;
                b.u[0] = pt2[(quad * 4 + 0) * RS + posp];
                b.u[1] = pt2[(quad * 4 + 1) * RS + posp];
                b.u[2] = pt2[(quad * 4 + 2) * RS + posp];
                b.u[3] = pt2[(quad * 4 + 3) * RS + posp];
                #pragma unroll
                for (int ct = 0; ct < 4; ++ct)
                    acc[ct][pt] = __builtin_amdgcn_mfma_f32_16x16x32_bf16(
                        a[ct], b.v, acc[ct][pt], 0, 0, 0);
            }
        }
    }

    #pragma unroll
    for (int ct = 0; ct < 4; ++ct) {
        int cobase = wave * 64 + ct * 16 + quad * 4;
        #pragma unroll
        for (int pt = 0; pt < 4; ++pt) {
            int px = pt * 16 + l15;
            int oh = oh0 + (px >> 3), ow = ow0 + (px & 7);
            #pragma unroll
            for (int r = 0; r < 4; ++r) {
                int co = cobase + r;
                float v = acc[ct][pt][r];
                if (WRITE_T) {
                    float o = fmaxf(bias[co] + v, 0.f);
                    outT[(size_t)img * (OH * OH * 256) + (size_t)(oh * OH + ow) * 256 + co]
                        = __float2bfloat16(o);
                } else {
                    atomicAdd(&outA[(size_t)img * (OH * OH * 256) + (size_t)co * (OH * OH)
                                    + oh * OH + ow], v);
                }
            }
        }
    }
}

// combine3 -> NHWC bf16
__global__ void combine3_k(const float* __restrict__ p3, const float* __restrict__ bias,
                           bf16* __restrict__ h3T)
{
    int idx = blockIdx.x * 256 + threadIdx.x;
    int px = idx & 255;
    int co = (idx >> 8) & 255;
    int img = idx >> 16;
    float v = fmaxf(bias[co] + p3[idx], 0.f);
    h3T[((size_t)img * 256 + px) * 256 + co] = __float2bfloat16(v);
}

// ===========================================================================
// conv4 MFMA: 3x3 s2 p1, 256->256 ch, 16->8, NHWC bf16, relu. grid 8.
// ===========================================================================
__global__ __launch_bounds__(256) void conv4m_k(const bf16* __restrict__ h3T,
        const bf16* __restrict__ wp4, const float* __restrict__ bias,
        bf16* __restrict__ h4T)
{
    int img = blockIdx.x;
    int t = threadIdx.x;
    int wave = t >> 6, lane = t & 63;
    int quad = lane >> 4, l15 = lane & 15;

    __shared__ uint pt[16 * 325];

    for (int i = t; i < 16 * 325; i += 256) pt[i] = 0;

    f32x4 zero = {0.f, 0.f, 0.f, 0.f};
    f32x4 acc[4][4];
    #pragma unroll
    for (int a = 0; a < 4; ++a)
        #pragma unroll
        for (int b = 0; b < 4; ++b) acc[a][b] = zero;

    const bf16* inb = h3T + (size_t)img * 65536;

    for (int ch = 0; ch < 8; ++ch) {
        __syncthreads();
        for (int e = t; e < 4096; e += 256) {
            int cp = e & 15, px = e >> 4;
            int py = px >> 4, qx = px & 15;
            uint v = *(const uint*)(inb + (size_t)px * 256 + ch * 32 + cp * 2);
            pt[cp * 325 + (py + 1) * 18 + qx + 1] = v;
        }
        __syncthreads();

        for (int tap = 0; tap < 9; ++tap) {
            int kh = tap / 3, kw = tap - kh * 3;
            const bf16* abase = wp4 + ((size_t)((tap * 32 + ch * 4 + quad) * 256)
                                       + wave * 64 + l15) * 8;
            short8 a[4];
            #pragma unroll
            for (int ct = 0; ct < 4; ++ct)
                a[ct] = *(const short8*)(abase + ct * 16 * 8);
            #pragma unroll
            for (int pq = 0; pq < 4; ++pq) {
                int pyo = 2 * pq + (l15 >> 3);
                int ipos = (2 * pyo + kh) * 18 + 2 * (l15 & 7) + kw;
                union { short8 v; uint u[4]; } b;
                b.u[0] = pt[(quad * 4 + 0) * 325 + ipos];
                b.u[1] = pt[(quad * 4 + 1) * 325 + ipos];
                b.u[2] = pt[(quad * 4 + 2) * 325 + ipos];
                b.u[3] = pt[(quad * 4 + 3) * 325 + ipos];
                #pragma unroll
                for (int ct = 0; ct < 4; ++ct)
                    acc[ct][pq] = __builtin_amdgcn_mfma_f32_16x16x32_bf16(
                        a[ct], b.v, acc[ct][pq], 0, 0, 0);
            }
        }
    }

    #pragma unroll
    for (int ct = 0; ct < 4; ++ct) {
        int cobase = wave * 64 + ct * 16 + quad * 4;
        #pragma unroll
        for (int pq = 0; pq < 4; ++pq) {
            int px = pq * 16 + l15;
            #pragma unroll
            for (int r = 0; r < 4; ++r) {
                int co = cobase + r;
                float v = fmaxf(bias[co] + acc[ct][pq][r], 0.f);
                h4T[((size_t)img * 64 + px) * 256 + co] = __float2bfloat16(v);
            }
        }
    }
}

// ===========================================================================
// res-a MFMA: t1 = conv1x3(relu(h)), 256->1024. grid 32.
// ===========================================================================
__global__ __launch_bounds__(256) void resam_k(const bf16* __restrict__ hT,
        const bf16* __restrict__ wpA, bf16* __restrict__ t1T)
{
    int bid = blockIdx.x;
    int img = bid >> 2, g = bid & 3;
    int t = threadIdx.x;
    int wave = t >> 6, lane = t & 63;
    int quad = lane >> 4, l15 = lane & 15;

    __shared__ uint ph[128 * 81];

    for (int i = t; i < 128 * 81; i += 256) ph[i] = 0;
    __syncthreads();
    const bf16* inb = hT + (size_t)img * 16384;
    for (int e = t; e < 8192; e += 256) {
        int cp = e & 127, px = e >> 7;
        uint v = relu2(*(const uint*)(inb + (size_t)px * 256 + cp * 2));
        ph[cp * 81 + (px >> 3) * 10 + (px & 7) + 1] = v;
    }
    __syncthreads();

    f32x4 zero = {0.f, 0.f, 0.f, 0.f};
    f32x4 acc[4][4];
    #pragma unroll
    for (int a = 0; a < 4; ++a)
        #pragma unroll
        for (int b = 0; b < 4; ++b) acc[a][b] = zero;

    for (int ch = 0; ch < 8; ++ch) {
        for (int tap = 0; tap < 3; ++tap) {
            const bf16* abase = wpA + ((size_t)(tap * 32 + ch * 4 + quad) * 1024
                                       + g * 256 + wave * 64 + l15) * 8;
            short8 a[4];
            #pragma unroll
            for (int ct = 0; ct < 4; ++ct)
                a[ct] = *(const short8*)(abase + ct * 16 * 8);
            #pragma unroll
            for (int pq = 0; pq < 4; ++pq) {
                int py = 2 * pq + (l15 >> 3);
                int pos = py * 10 + (l15 & 7) + tap;
                union { short8 v; uint u[4]; } b;
                b.u[0] = ph[(ch * 16 + quad * 4 + 0) * 81 + pos];
                b.u[1] = ph[(ch * 16 + quad * 4 + 1) * 81 + pos];
                b.u[2] = ph[(ch * 16 + quad * 4 + 2) * 81 + pos];
                b.u[3] = ph[(ch * 16 + quad * 4 + 3) * 81 + pos];
                #pragma unroll
                for (int ct = 0; ct < 4; ++ct)
                    acc[ct][pq] = __builtin_amdgcn_mfma_f32_16x16x32_bf16(
                        a[ct], b.v, acc[ct][pq], 0, 0, 0);
            }
        }
    }

    #pragma unroll
    for (int ct = 0; ct < 4; ++ct) {
        int cobase = g * 256 + wave * 64 + ct * 16 + quad * 4;
        #pragma unroll
        for (int pq = 0; pq < 4; ++pq) {
            int px = pq * 16 + l15;
            #pragma unroll
            for (int r = 0; r < 4; ++r)
                t1T[((size_t)img * 64 + px) * 1024 + cobase + r]
                    = __float2bfloat16(acc[ct][pq][r]);
        }
    }
}

// ===========================================================================
// res-b MFMA: h_new = h_old + conv1x1(relu(t1)), 1024->256. grid 8.
// ===========================================================================
__global__ __launch_bounds__(256) void resbm_k(const bf16* __restrict__ holdT,
        const bf16* __restrict__ t1T, const bf16* __restrict__ wpB,
        bf16* __restrict__ hnewT)
{
    int img = blockIdx.x;
    int t = threadIdx.x;
    int wave = t >> 6, lane = t & 63;
    int quad = lane >> 4, l15 = lane & 15;

    __shared__ uint pb[256 * 65];

    f32x4 zero = {0.f, 0.f, 0.f, 0.f};
    f32x4 acc[4][4];
    #pragma unroll
    for (int a = 0; a < 4; ++a)
        #pragma unroll
        for (int b = 0; b < 4; ++b) acc[a][b] = zero;

    const bf16* inb = t1T + (size_t)img * 65536;

    for (int s = 0; s < 2; ++s) {
        __syncthreads();
        for (int e = t; e < 16384; e += 256) {
            int cp = e & 255, px = e >> 8;
            uint v = relu2(*(const uint*)(inb + (size_t)px * 1024 + s * 512 + cp * 2));
            pb[cp * 65 + px] = v;
        }
        __syncthreads();

        for (int chl = 0; chl < 16; ++chl) {
            int ch = s * 16 + chl;
            const bf16* abase = wpB + ((size_t)(ch * 4 + quad) * 256
                                       + wave * 64 + l15) * 8;
            short8 a[4];
            #pragma unroll
            for (int ct = 0; ct < 4; ++ct)
                a[ct] = *(const short8*)(abase + ct * 16 * 8);
            #pragma unroll
            for (int pq = 0; pq < 4; ++pq) {
                int px = pq * 16 + l15;
                union { short8 v; uint u[4]; } b;
                b.u[0] = pb[(chl * 16 + quad * 4 + 0) * 65 + px];
                b.u[1] = pb[(chl * 16 + quad * 4 + 1) * 65 + px];
                b.u[2] = pb[(chl * 16 + quad * 4 + 2) * 65 + px];
                b.u[3] = pb[(chl * 16 + quad * 4 + 3) * 65 + px];
                #pragma unroll
                for (int ct = 0; ct < 4; ++ct)
                    acc[ct][pq] = __builtin_amdgcn_mfma_f32_16x16x32_bf16(
                        a[ct], b.v, acc[ct][pq], 0, 0, 0);
            }
        }
    }

    #pragma unroll
    for (int ct = 0; ct < 4; ++ct) {
        int cobase = wave * 64 + ct * 16 + quad * 4;
        #pragma unroll
        for (int pq = 0; pq < 4; ++pq) {
            int px = pq * 16 + l15;
            #pragma unroll
            for (int r = 0; r < 4; ++r) {
                int co = cobase + r;
                size_t o = ((size_t)img * 64 + px) * 256 + co;
                float v = b2f(holdT[o]) + acc[ct][pq][r];
                hnewT[o] = __float2bfloat16(v);
            }
        }
    }
}

__global__ void embnorm_k(const float* __restrict__ emb, float* __restrict__ en)
{
    int k = blockIdx.x * 256 + threadIdx.x;
    const float* e = emb + (size_t)k * 256;
    float s = 0.f;
    for (int d = 0; d < 256; ++d) { float v = e[d]; s += v * v; }
    en[k] = s;
}

// VQ: one block per latent row (512). Reads h6T NHWC bf16 (relu'd here).
__global__ void vq_k(const bf16* __restrict__ h6T, const float* __restrict__ emb,
                     const float* __restrict__ en, float* __restrict__ out,
                     float* __restrict__ mse_acc, int* __restrict__ hist)
{
    int row = blockIdx.x;
    int b = row >> 6, y = (row >> 3) & 7, xx = row & 7;
    int t = threadIdx.x;
    __shared__ float lat[256];
    __shared__ float sdist[256];
    __shared__ int   sidx[256];

    float l = fmaxf(b2f(h6T[(size_t)row * 256 + t]), 0.f);
    lat[t] = l;
    __syncthreads();

    float d0 = 0.f, d1 = 0.f;
    const float* e0 = emb + (size_t)t * 256;
    const float* e1 = emb + (size_t)(t + 256) * 256;
    for (int d = 0; d < 256; ++d) {
        float lv = lat[d];
        d0 += lv * e0[d];
        d1 += lv * e1[d];
    }
    d0 = en[t] - 2.f * d0;
    d1 = en[t + 256] - 2.f * d1;
    float best_d = d0; int best_i = t;
    if (d1 < best_d) { best_d = d1; best_i = t + 256; }
    sdist[t] = best_d; sidx[t] = best_i;
    __syncthreads();
    for (int s = 128; s > 0; s >>= 1) {
        if (t < s) {
            float od = sdist[t + s]; int oi = sidx[t + s];
            if (od < sdist[t] || (od == sdist[t] && oi < sidx[t])) {
                sdist[t] = od; sidx[t] = oi;
            }
        }
        __syncthreads();
    }
    int idx = sidx[0];

    float q = emb[(size_t)idx * 256 + t];
    out[((size_t)(b * 256 + t) * 8 + y) * 8 + xx] = q;
    float diff = q - lat[t];
    __syncthreads();
    sdist[t] = diff * diff;
    __syncthreads();
    for (int s = 128; s > 0; s >>= 1) {
        if (t < s) sdist[t] += sdist[t + s];
        __syncthreads();
    }
    if (t == 0) {
        atomicAdd(mse_acc, sdist[0]);
        atomicAdd(&hist[idx], 1);
    }
}

__global__ void final_k(const float* __restrict__ mse_acc, const int* __restrict__ hist,
                        float* __restrict__ out)
{
    __shared__ float sh[512];
    int t = threadIdx.x;
    float p = (float)hist[t] / 512.f;
    sh[t] = p * logf(p + 1e-10f);
    __syncthreads();
    for (int s = 256; s > 0; s >>= 1) {
        if (t < s) sh[t] += sh[t + s];
        __syncthreads();
    }
    if (t == 0) {
        float loss = 2.f * mse_acc[0] / (512.f * 256.f);
        float perp = expf(-sh[0]);
        out[131072] = loss;
        out[131073] = perp;
    }
}

// ===========================================================================
extern "C" void kernel_launch(void* const* d_in, const int* in_sizes, int n_in,
                              void* d_out, int out_size, void* d_ws, size_t ws_size,
                              hipStream_t stream)
{
    const float* x    = (const float*)d_in[0];
    const float* w_in = (const float*)d_in[1];
    const float* b_in = (const float*)d_in[2];
    const float* w_h1 = (const float*)d_in[3];
    const float* b_h1 = (const float*)d_in[4];
    const float* w_h2 = (const float*)d_in[5];
    const float* b_h2 = (const float*)d_in[6];
    const float* w_h3 = (const float*)d_in[7];
    const float* b_h3 = (const float*)d_in[8];
    const float* r0w1 = (const float*)d_in[9];
    const float* r0w2 = (const float*)d_in[10];
    const float* r1w1 = (const float*)d_in[11];
    const float* r1w2 = (const float*)d_in[12];
    const float* emb  = (const float*)d_in[13];
    float* out = (float*)d_out;

    char* ws = (char*)d_ws;
    size_t off = 0;
    auto alloc = [&](size_t bytes) -> void* {
        void* p = ws + off;
        off += (bytes + 255) & ~(size_t)255;
        return p;
    };

    float* en  = (float*)alloc(512 * 4);
    float* mse = (float*)alloc(256);
    int*  hist = (int*)alloc(512 * 4);
    float* p3  = (float*)alloc(524288ull * 4);
    bf16* h3T  = (bf16*)alloc(524288ull * 2);
    bf16* h4T  = (bf16*)alloc(131072ull * 2);
    bf16* t1T  = (bf16*)alloc(524288ull * 2);
    bf16* h5T  = (bf16*)alloc(131072ull * 2);
    bf16* h6T  = (bf16*)alloc(131072ull * 2);
    bf16* wp1  = (bf16*)alloc(8192ull * 2);        // conv1 8*128*8
    bf16* wpack2 = (bf16*)alloc(1638400ull * 2);
    bf16* wpack3 = (bf16*)alloc(3276800ull * 2);
    bf16* wp4  = (bf16*)alloc(589824ull * 2);
    bf16* wpA0 = (bf16*)alloc(786432ull * 2);
    bf16* wpA1 = (bf16*)alloc(786432ull * 2);
    bf16* wpB0 = (bf16*)alloc(262144ull * 2);
    bf16* wpB1 = (bf16*)alloc(262144ull * 2);
    bf16* h2T  = (bf16*)alloc(8388608ull * 2);
    size_t base_end = off;

    const size_t H1TI = 8388608;
    size_t needFull = base_end + H1TI * 8 * 2 + 4096;
    bool full = ws_size >= needFull;
    bf16* h1T = (bf16*)alloc(full ? H1TI * 8 * 2 : H1TI * 2);

    hipMemsetAsync(mse, 0, 4, stream);
    hipMemsetAsync(hist, 0, 512 * 4, stream);
    hipMemsetAsync(p3, 0, 524288ull * 4, stream);

    wpack1_k<<<32, 256, 0, stream>>>(w_in, wp1);
    wpack_k<128><<<6400, 256, 0, stream>>>(w_h1, wpack2);
    wpack_k<256><<<12800, 256, 0, stream>>>(w_h2, wpack3);
    wpack_g<9, 256, 32><<<2304, 256, 0, stream>>>(w_h3, wp4);
    wpack_g<3, 1024, 32><<<3072, 256, 0, stream>>>(r0w1, wpA0);
    wpack_g<3, 1024, 32><<<3072, 256, 0, stream>>>(r1w1, wpA1);
    wpack_g<1, 256, 128><<<1024, 256, 0, stream>>>(r0w2, wpB0);
    wpack_g<1, 256, 128><<<1024, 256, 0, stream>>>(r1w2, wpB1);

    if (full) {
        conv1m_k<<<4096, 256, 0, stream>>>(x, wp1, b_in, h1T);
        conv_mfma2_k<256, 64, 128, 1, true><<<512, 256, 0, stream>>>(
            h1T, wpack2, b_h1, nullptr, h2T);
    } else {
        for (int n = 0; n < 8; ++n) {
            conv1m_k<<<512, 256, 0, stream>>>(x + (size_t)n * 786432, wp1, b_in, h1T);
            conv_mfma2_k<256, 64, 128, 1, true><<<64, 256, 0, stream>>>(
                h1T, wpack2, b_h1, nullptr, h2T + (size_t)n * 1048576);
        }
    }

    conv_mfma2_k<64, 16, 256, 8, false><<<256, 256, 0, stream>>>(
        h2T, wpack3, b_h2, p3, nullptr);
    combine3_k<<<2048, 256, 0, stream>>>(p3, b_h2, h3T);

    conv4m_k<<<8, 256, 0, stream>>>(h3T, wp4, b_h3, h4T);
    resam_k<<<32, 256, 0, stream>>>(h4T, wpA0, t1T);
    resbm_k<<<8, 256, 0, stream>>>(h4T, t1T, wpB0, h5T);
    resam_k<<<32, 256, 0, stream>>>(h5T, wpA1, t1T);
    resbm_k<<<8, 256, 0, stream>>>(h5T, t1T, wpB1, h6T);

    embnorm_k<<<2, 256, 0, stream>>>(emb, en);
    vq_k<<<512, 256, 0, stream>>>(h6T, emb, en, out, mse, hist);
    final_k<<<1, 512, 0, stream>>>(mse, hist, out);
}